// Round 1
// baseline (601.069 us; speedup 1.0000x reference)
//
#include <hip/hip_runtime.h>
#include <hip/hip_fp16.h>
#include <math.h>

// ---------------------------------------------------------------------------
// TAGConv x2 + linear + sigmoid, 500k nodes / 4M edges.
// Round 15: degree-sorted SLOT space. build_kernel counting-sorts each
// 2048-node bucket by ng (groups-of-8 count); all per-node state + payload
// live in sorted slot order, and remap_kernel rewrites payload src ids into
// slot space. Every wave in every hop kernel now has uniform ng (no
// exec-masked gather iterations), with coalescing identical to node space.
// Scaled-state propagation z_k = dinv .* h_k (fp16 state); MFMA epilogue;
// LDS counting-sort build (R13); paired-group gathers (R14).
// ---------------------------------------------------------------------------

#define TB 256
#define TBLD 1024
#define TBIN 1024
#define BSHIFT 11
#define BW 2048             // nodes per bucket
#define CAPB 17408          // binBuf cap (raw recs; mean 16384, ~8 sigma)
#define CAP 26624           // payload cap per bucket (8-padded; mean ~23.6k)
#define HALF_CAP 20480      // ord staging per slot-half (sorted halves imbalance)
#define BIN_CHUNK 16384     // edges per block in bin_kernel
#define WQ 8191.0f          // 13-bit weight quantization

typedef _Float16 half8 __attribute__((ext_vector_type(8)));
typedef float floatx4 __attribute__((ext_vector_type(4)));

// Phase 1: one-pass binning, register-staged dst. rec: {src|ld<<19, w-bits}
__global__ __launch_bounds__(TBIN) void bin_kernel(
        const int* __restrict__ src, const int* __restrict__ dst,
        const float* __restrict__ w, int* __restrict__ binCount,
        uint2* __restrict__ binBuf, int E, int NB) {
    __shared__ int bcnt[256];
    __shared__ int bbase[256];
    for (int i = threadIdx.x; i < 256; i += TBIN) bcnt[i] = 0;
    __syncthreads();

    int base = blockIdx.x * BIN_CHUNK;
    int d[16];
#pragma unroll
    for (int j = 0; j < 16; j++) {
        int e = base + threadIdx.x + j * TBIN;
        d[j] = (e < E) ? dst[e] : -1;
        if (d[j] >= 0) atomicAdd(&bcnt[d[j] >> BSHIFT], 1);
    }
    __syncthreads();
    for (int i = threadIdx.x; i < NB; i += TBIN) {
        int c = bcnt[i];
        bbase[i] = c ? atomicAdd(&binCount[i], c) : 0;
        bcnt[i] = 0;   // reuse as local cursor
    }
    __syncthreads();
#pragma unroll
    for (int j = 0; j < 16; j++) {
        if (d[j] >= 0) {
            int e = base + threadIdx.x + j * TBIN;
            int b = d[j] >> BSHIFT;
            int off = bbase[b] + atomicAdd(&bcnt[b], 1);
            if (off < CAPB) {
                binBuf[(size_t)b * CAPB + off] =
                    make_uint2((unsigned)src[e] | ((unsigned)(d[j] & (BW - 1)) << 19),
                               __float_as_uint(w[e]));
            }
        }
    }
}

// Phase 2: one block per bucket. Count -> ng-sort (16-bin counting sort)
// -> slot-ordered scan (8-padded) -> per-slot outputs -> for each 1024-slot
// half: LDS counting-sort index, then coalesced payload stream-out.
// Payload src stays in NODE space here; remap_kernel converts to slot space.
__global__ __launch_bounds__(TBLD) void build_kernel(
        const int* __restrict__ binCount, const uint2* __restrict__ binBuf,
        unsigned* __restrict__ payload, int* __restrict__ seg,
        float* __restrict__ dinv2, float* __restrict__ rdinv,
        int* __restrict__ order, int* __restrict__ inv,
        const float* __restrict__ x, __half2* __restrict__ z0,
        int N, int NB) {
    __shared__ int   cnt[BW];
    __shared__ float wsum[BW];
    __shared__ int   start[BW];            // slot-indexed exclusive scan
    __shared__ unsigned short pos[BW];     // node-local -> slot-local
    __shared__ unsigned short ord[HALF_CAP];
    __shared__ int   tmp[TBLD];
    __shared__ int   hist[48];             // 0..15 hist | 16..31 base | 32..47 cursor
    __shared__ int   stot;
    int b = blockIdx.x;
    int nBase = b << BSHIFT;
    int nCount = min(BW, N - nBase);
    int m = min(binCount[b], CAPB);

    for (int i = threadIdx.x; i < BW; i += TBLD) { cnt[i] = 0; wsum[i] = 0.0f; }
    if (threadIdx.x < 48) hist[threadIdx.x] = 0;
    __syncthreads();

    const uint2* recs = binBuf + (size_t)b * CAPB;
    for (int i = threadIdx.x; i < m; i += TBLD) {
        uint2 r = recs[i];
        int ld = r.x >> 19;
        atomicAdd(&cnt[ld], 1);
        atomicAdd(&wsum[ld], __uint_as_float(r.y));
    }
    __syncthreads();

    // ---- degree sort within bucket: key = min(ng, 15), ascending ----
    for (int i = threadIdx.x; i < nCount; i += TBLD)
        atomicAdd(&hist[min((cnt[i] + 7) >> 3, 15)], 1);
    __syncthreads();
    if (threadIdx.x == 0) {
        int run = 0;
        for (int j = 0; j < 16; j++) { hist[16 + j] = run; run += hist[j]; }
    }
    __syncthreads();
    for (int i = threadIdx.x; i < nCount; i += TBLD) {
        int k = min((cnt[i] + 7) >> 3, 15);
        int p = hist[16 + k] + atomicAdd(&hist[32 + k], 1);
        pos[i] = (unsigned short)p;
        order[nBase + p] = nBase + i;
        inv[nBase + i] = nBase + p;
    }
    __syncthreads();

    // per-node stats -> slot space (frees wsum afterwards)
    for (int i = threadIdx.x; i < nCount; i += TBLD) {
        int s = nBase + pos[i];
        float dsum = wsum[i];
        float di = (dsum > 0.0f) ? rsqrtf(dsum) : 0.0f;
        dinv2[s] = di * di;
        rdinv[s] = dsum * di;            // sqrt(deg), 0 if deg==0
        float2 xv = reinterpret_cast<const float2*>(x)[nBase + i];
        z0[s] = __float22half2_rn(make_float2(di * xv.x, di * xv.y));
    }
    __syncthreads();

    // slot-ordered padded counts (reuse wsum as int scnt)
    int* scnt = (int*)wsum;
    for (int s = threadIdx.x; s < BW; s += TBLD) scnt[s] = 0;
    __syncthreads();
    for (int i = threadIdx.x; i < nCount; i += TBLD)
        scnt[pos[i]] = (cnt[i] + 7) & ~7;
    __syncthreads();

    // exclusive scan of 8-padded counts over slot space, 2 elems/thread
    int b2i = threadIdx.x * 2;
    int c0 = scnt[b2i];
    int c1 = scnt[b2i + 1];
    int ssum = c0 + c1;
    tmp[threadIdx.x] = ssum;
    __syncthreads();
    for (int off = 1; off < TBLD; off <<= 1) {
        int t = (threadIdx.x >= off) ? tmp[threadIdx.x - off] : 0;
        __syncthreads();
        tmp[threadIdx.x] += t;
        __syncthreads();
    }
    int run = tmp[threadIdx.x] - ssum;
    start[b2i] = run;
    start[b2i + 1] = run + c0;
    if (threadIdx.x == TBLD - 1) stot = run + ssum;   // total padded size
    __syncthreads();

    int tot = min(stot, CAP);
    int mid = (nCount > 1024) ? min(start[1024], CAP) : tot;

    // seg (slot space)
    for (int i = threadIdx.x; i < nCount; i += TBLD) {
        int p = pos[i];
        int st = start[p];
        int cc = cnt[i];
        int ng = (cc + 7) >> 3;
        if (st >= CAP) { ng = 0; }
        else if (st + 8 * ng > CAP) { ng = (CAP - st) >> 3; }
        seg[nBase + p] = (st >> 3) | (ng << 16);
    }
    __syncthreads();

    size_t pbase = (size_t)b * CAP;
    for (int half = 0; half < 2; half++) {
        int lo = half << 10, hi = lo + 1024;
        int pbeg = half ? mid : 0;
        int pend = half ? tot : mid;
        int limit = pend - pbeg;
        int limc = min(limit, HALF_CAP);

        // cursors (reuse cnt, node-local index) + ord init
        for (int i = threadIdx.x; i < nCount; i += TBLD) cnt[i] = start[pos[i]] - pbeg;
        for (int j = threadIdx.x; j < limc; j += TBLD) ord[j] = 0xFFFF;
        __syncthreads();

        // counting-sort index pass (slot-half membership via pos)
        for (int i = threadIdx.x; i < m; i += TBLD) {
            uint2 r = recs[i];
            int ld = r.x >> 19;
            int sl = pos[ld];
            if (sl >= lo && sl < hi) {
                int p = atomicAdd(&cnt[ld], 1);
                if ((unsigned)p < (unsigned)limc) ord[p] = (unsigned short)i;
            }
        }
        __syncthreads();

        // coalesced stream-out (random reads hit L2-resident recs)
        for (int j = threadIdx.x; j < limc; j += TBLD) {
            unsigned short oi = ord[j];
            unsigned word = 0;
            if (oi != 0xFFFF) {
                uint2 r = recs[oi];
                unsigned q = (unsigned)__float2int_rn(__uint_as_float(r.y) * WQ);
                word = (r.x & 0x7FFFFu) | (q << 19);
            }
            payload[pbase + pbeg + j] = word;
        }
        for (int j = limc + threadIdx.x; j < limit; j += TBLD)
            payload[pbase + pbeg + j] = 0;
        __syncthreads();
    }
}

// Phase 3: rewrite payload src ids (node space -> slot space). Pad words
// (w==0) carry weight 0 so an arbitrary remapped src is harmless.
__global__ void remap_kernel(uint4* __restrict__ payload, const int* __restrict__ inv,
                             int nquads, int N) {
    int i = blockIdx.x * TB + threadIdx.x;
    if (i >= nquads) return;
    uint4 v = payload[i];
    v.x = (v.x & ~0x7FFFFu) | (unsigned)inv[min((int)(v.x & 0x7FFFFu), N - 1)];
    v.y = (v.y & ~0x7FFFFu) | (unsigned)inv[min((int)(v.y & 0x7FFFFu), N - 1)];
    v.z = (v.z & ~0x7FFFFu) | (unsigned)inv[min((int)(v.z & 0x7FFFFu), N - 1)];
    v.w = (v.w & ~0x7FFFFu) | (unsigned)inv[min((int)(v.w & 0x7FFFFu), N - 1)];
    payload[i] = v;
}

// ---- gather helpers: full groups of 8, paired-group MLP, no masks ---------

// C=2
__device__ __forceinline__ void gacc2m(const unsigned* __restrict__ payload,
                                       const __half2* __restrict__ zin,
                                       int beg, int ng, float& ax, float& ay) {
    int g = 0;
    for (; g + 2 <= ng; g += 2, beg += 16) {
        uint4 r0 = *reinterpret_cast<const uint4*>(payload + beg);
        uint4 r1 = *reinterpret_cast<const uint4*>(payload + beg + 4);
        uint4 r2 = *reinterpret_cast<const uint4*>(payload + beg + 8);
        uint4 r3 = *reinterpret_cast<const uint4*>(payload + beg + 12);
        unsigned r[16] = {r0.x, r0.y, r0.z, r0.w, r1.x, r1.y, r1.z, r1.w,
                          r2.x, r2.y, r2.z, r2.w, r3.x, r3.y, r3.z, r3.w};
        __half2 v[16];
#pragma unroll
        for (int j = 0; j < 16; j++) v[j] = zin[r[j] & 0x7FFFFu];
#pragma unroll
        for (int j = 0; j < 16; j++) {
            float wv = (float)(r[j] >> 19) * (1.0f / WQ);
            float2 f = __half22float2(v[j]);
            ax += wv * f.x;
            ay += wv * f.y;
        }
    }
    if (g < ng) {
        uint4 r0 = *reinterpret_cast<const uint4*>(payload + beg);
        uint4 r1 = *reinterpret_cast<const uint4*>(payload + beg + 4);
        unsigned r[8] = {r0.x, r0.y, r0.z, r0.w, r1.x, r1.y, r1.z, r1.w};
        __half2 v[8];
#pragma unroll
        for (int j = 0; j < 8; j++) v[j] = zin[r[j] & 0x7FFFFu];
#pragma unroll
        for (int j = 0; j < 8; j++) {
            float wv = (float)(r[j] >> 19) * (1.0f / WQ);
            float2 f = __half22float2(v[j]);
            ax += wv * f.x;
            ay += wv * f.y;
        }
    }
}

// C=4 (quarter-row); ubase = uin + 4*quarter.
__device__ __forceinline__ void gacc4(const unsigned* __restrict__ payload,
                                      const __half* __restrict__ ubase,
                                      int beg, int ng, float* __restrict__ h) {
    int g = 0;
    for (; g + 2 <= ng; g += 2, beg += 16) {
        uint4 r0 = *reinterpret_cast<const uint4*>(payload + beg);
        uint4 r1 = *reinterpret_cast<const uint4*>(payload + beg + 4);
        uint4 r2 = *reinterpret_cast<const uint4*>(payload + beg + 8);
        uint4 r3 = *reinterpret_cast<const uint4*>(payload + beg + 12);
        unsigned r[16] = {r0.x, r0.y, r0.z, r0.w, r1.x, r1.y, r1.z, r1.w,
                          r2.x, r2.y, r2.z, r2.w, r3.x, r3.y, r3.z, r3.w};
        float2 a[16];
#pragma unroll
        for (int j = 0; j < 16; j++)
            a[j] = *reinterpret_cast<const float2*>(ubase + 16LL * (int)(r[j] & 0x7FFFFu));
#pragma unroll
        for (int j = 0; j < 16; j++) {
            float wv = (float)(r[j] >> 19) * (1.0f / WQ);
            const __half2* hp = reinterpret_cast<const __half2*>(&a[j]);
            float2 v0 = __half22float2(hp[0]);
            float2 v1 = __half22float2(hp[1]);
            h[0] += wv * v0.x;
            h[1] += wv * v0.y;
            h[2] += wv * v1.x;
            h[3] += wv * v1.y;
        }
    }
    if (g < ng) {
        uint4 r0 = *reinterpret_cast<const uint4*>(payload + beg);
        uint4 r1 = *reinterpret_cast<const uint4*>(payload + beg + 4);
        unsigned r[8] = {r0.x, r0.y, r0.z, r0.w, r1.x, r1.y, r1.z, r1.w};
        float2 a[8];
#pragma unroll
        for (int j = 0; j < 8; j++)
            a[j] = *reinterpret_cast<const float2*>(ubase + 16LL * (int)(r[j] & 0x7FFFFu));
#pragma unroll
        for (int j = 0; j < 8; j++) {
            float wv = (float)(r[j] >> 19) * (1.0f / WQ);
            const __half2* hp = reinterpret_cast<const __half2*>(&a[j]);
            float2 v0 = __half22float2(hp[0]);
            float2 v1 = __half22float2(hp[1]);
            h[0] += wv * v0.x;
            h[1] += wv * v0.y;
            h[2] += wv * v1.x;
            h[3] += wv * v1.y;
        }
    }
}

// ----------------------------------------------------------------------------
// All hop kernels operate purely in SLOT space (payload srcs are slots too).

// z_k[s] = dinv2[s] * sum w * z_{k-1}[src]   (C=2, fp16 state), k=1..3
__global__ void hop2_kernel(const int* __restrict__ seg, const unsigned* __restrict__ payload,
                            const __half2* __restrict__ zin, const float* __restrict__ dinv2,
                            __half2* __restrict__ zout, int N) {
    int s = blockIdx.x * TB + threadIdx.x;
    if (s >= N) return;
    int sp = seg[s];
    int beg = (s >> BSHIFT) * CAP + ((sp & 0xFFFF) << 3);
    int ng = sp >> 16;
    float ax = 0.0f, ay = 0.0f;
    gacc2m(payload, zin, beg, ng, ax, ay);
    float sc = dinv2[s];
    zout[s] = __float22half2_rn(make_float2(ax * sc, ay * sc));
}

// Fused hop2 k=4 + conv1 epilogue
__global__ void hop2_final_kernel(const int* __restrict__ seg, const unsigned* __restrict__ payload,
                                  const __half2* __restrict__ zbuf,   // z0..z3
                                  const float* __restrict__ x, const int* __restrict__ order,
                                  const float* __restrict__ rdinv, const float* __restrict__ dinv2,
                                  const float* __restrict__ W1, const float* __restrict__ b1,
                                  __half* __restrict__ g0, __half* __restrict__ u0, int N) {
    __shared__ float Ws[160];
    __shared__ float bs[16];
    for (int i = threadIdx.x; i < 160; i += blockDim.x) Ws[i] = W1[i];
    if (threadIdx.x < 16) bs[threadIdx.x] = b1[threadIdx.x];
    __syncthreads();

    int s = blockIdx.x * TB + threadIdx.x;
    if (s >= N) return;

    int sp = seg[s];
    int beg = (s >> BSHIFT) * CAP + ((sp & 0xFFFF) << 3);
    int ng = sp >> 16;
    const __half2* z3 = zbuf + (size_t)3 * N;
    float ax = 0.0f, ay = 0.0f;
    gacc2m(payload, z3, beg, ng, ax, ay);
    float sc = dinv2[s];
    float rd = rdinv[s];

    float coeff[10];
    {
        int n = order[s];
        float2 v = reinterpret_cast<const float2*>(x)[n];
        coeff[0] = v.x; coeff[1] = v.y;
    }
#pragma unroll
    for (int k = 1; k <= 3; k++) {
        float2 v = __half22float2(zbuf[(size_t)k * N + s]);
        coeff[2 * k + 0] = rd * v.x;
        coeff[2 * k + 1] = rd * v.y;
    }
    coeff[8] = rd * sc * ax;
    coeff[9] = rd * sc * ay;

    float o[16];
#pragma unroll
    for (int c = 0; c < 16; c++) o[c] = bs[c];
#pragma unroll
    for (int j = 0; j < 10; j++) {
        float cf = coeff[j];
#pragma unroll
        for (int c = 0; c < 16; c++) o[c] += cf * Ws[j * 16 + c];
    }
#pragma unroll
    for (int c = 0; c < 16; c++) o[c] = fmaxf(o[c], 0.0f);

    float di = sc * rd;   // = dinv (0 for deg-0 nodes)

    __half2 gp[8], up[8];
#pragma unroll
    for (int q = 0; q < 8; q++) {
        gp[q] = __float22half2_rn(make_float2(o[2 * q], o[2 * q + 1]));
        up[q] = __float22half2_rn(make_float2(di * o[2 * q], di * o[2 * q + 1]));
    }
    float4* gw = reinterpret_cast<float4*>(g0 + 16LL * s);
    gw[0] = *reinterpret_cast<float4*>(&gp[0]);
    gw[1] = *reinterpret_cast<float4*>(&gp[4]);
    float4* uw = reinterpret_cast<float4*>(u0 + 16LL * s);
    uw[0] = *reinterpret_cast<float4*>(&up[0]);
    uw[1] = *reinterpret_cast<float4*>(&up[4]);
}

// u_k = dinv2 * sum w * u_{k-1}[src]; 4 threads per slot (4 channels each)
__global__ void hop16_kernel(const int* __restrict__ seg, const unsigned* __restrict__ payload,
                             const __half* __restrict__ uin, const float* __restrict__ dinv2,
                             __half* __restrict__ uout, int N) {
    int gid = blockIdx.x * TB + threadIdx.x;
    int s = gid >> 2, quarter = gid & 3;
    if (s >= N) return;
    int sp = seg[s];
    int beg = (s >> BSHIFT) * CAP + ((sp & 0xFFFF) << 3);
    int ng = sp >> 16;

    float h[4] = {0.0f, 0.0f, 0.0f, 0.0f};
    gacc4(payload, uin + 4 * quarter, beg, ng, h);

    float sc = dinv2[s];
    __half2 p[2];
    p[0] = __float22half2_rn(make_float2(h[0] * sc, h[1] * sc));
    p[1] = __float22half2_rn(make_float2(h[2] * sc, h[3] * sc));
    *reinterpret_cast<float2*>(uout + 16LL * s + 4 * quarter) = *reinterpret_cast<float2*>(&p[0]);
}

// Fused hop16 k=4 + conv2 epilogue via MFMA + endLinear + sigmoid.
// Wave = 16 slots x 4 quads; slot=lane&15, quarter=lane>>4. Output scattered
// through order[] back to node ids.
__global__ void hop16_final_kernel(const int* __restrict__ seg, const unsigned* __restrict__ payload,
                                   const __half* __restrict__ g0, const __half* __restrict__ ubuf,
                                   const int* __restrict__ order,
                                   const float* __restrict__ rdinv, const float* __restrict__ dinv2,
                                   const float* __restrict__ W2, const float* __restrict__ b2,
                                   const float* __restrict__ Wend, float* __restrict__ out, int N) {
    int lane = threadIdx.x & 63;
    int wave = threadIdx.x >> 6;
    int q = lane >> 4;           // quad -> K-chunk
    int nn = lane & 15;          // slot row m / output column n
    int slot_base = (blockIdx.x * 4 + wave) * 16;
    int slot = slot_base + nn;
    int slotc = min(slot, N - 1);

    // B fragments: lane supplies B[K=32t+8q+i][n=nn] from W2 (fp32->fp16)
    half8 bf[3];
#pragma unroll
    for (int t = 0; t < 3; t++) {
        half8 bv;
#pragma unroll
        for (int i = 0; i < 8; i++) {
            int K = 32 * t + 8 * q + i;
            K = (K < 80) ? K : 79;          // pad rows never used (A=0 there)
            bv[i] = (_Float16)W2[K * 16 + nn];
        }
        bf[t] = bv;
    }
    float bsv = b2[nn];
    float wev = Wend[nn];

    // gather k=4 term: h = quarter q (channels 4q..4q+3) of slot's u4 row
    int sp = seg[slotc];
    int beg = (slotc >> BSHIFT) * CAP + ((sp & 0xFFFF) << 3);
    int ng = sp >> 16;
    const __half* u3 = ubuf + (size_t)3 * 16 * N;
    float h[4] = {0.0f, 0.0f, 0.0f, 0.0f};
    gacc4(payload, u3 + 4 * q, beg, ng, h);

    float rd = rdinv[slotc];
    float sc = dinv2[slotc];

    // A fragment t=0: q0,q1 -> g0 (raw); q2,q3 -> u1 (x rd)
    const __half* a0p = ((q < 2) ? g0 : (ubuf + (size_t)16 * N)) + 16LL * slotc + 8 * (q & 1);
    half8 a0 = *reinterpret_cast<const half8*>(a0p);
    a0 = a0 * ((q >= 2) ? (_Float16)rd : (_Float16)1.0f);

    // A fragment t=1: q0,q1 -> u2; q2,q3 -> u3 (all x rd)
    const __half* a1p = ((q < 2) ? (ubuf + (size_t)2 * 16 * N) : (ubuf + (size_t)3 * 16 * N))
                        + 16LL * slotc + 8 * (q & 1);
    half8 a1 = *reinterpret_cast<const half8*>(a1p);
    a1 = a1 * (_Float16)rd;

    // A fragment t=2: q0,q1 -> h (x rd*sc) via shfl repack; q2,q3 -> zero pad
    float s4 = rd * sc;
    __half2 hh0 = __floats2half2_rn(h[0] * s4, h[1] * s4);
    __half2 hh1 = __floats2half2_rn(h[2] * s4, h[3] * s4);
    int p0, p1;
    p0 = *reinterpret_cast<int*>(&hh0);
    p1 = *reinterpret_cast<int*>(&hh1);
    int srcA = (nn + (q << 5)) & 63;   // q0: quarters 0,1 ; q1: quarters 2,3
    int srcB = (srcA + 16) & 63;
    int lo0 = __shfl(p0, srcA, 64);
    int lo1 = __shfl(p1, srcA, 64);
    int hi0 = __shfl(p0, srcB, 64);
    int hi1 = __shfl(p1, srcB, 64);
    if (q >= 2) { lo0 = 0; lo1 = 0; hi0 = 0; hi1 = 0; }
    union { half8 v; int u[4]; } a2;
    a2.u[0] = lo0; a2.u[1] = lo1; a2.u[2] = hi0; a2.u[3] = hi1;

    floatx4 acc = {bsv, bsv, bsv, bsv};
    acc = __builtin_amdgcn_mfma_f32_16x16x32_f16(a0, bf[0], acc, 0, 0, 0);
    acc = __builtin_amdgcn_mfma_f32_16x16x32_f16(a1, bf[1], acc, 0, 0, 0);
    acc = __builtin_amdgcn_mfma_f32_16x16x32_f16(a2.v, bf[2], acc, 0, 0, 0);

    // D[m = q*4+reg][n = nn]: relu, dot with Wend over n, sigmoid, store
    float svals[4];
#pragma unroll
    for (int r = 0; r < 4; r++) {
        float o = fmaxf(acc[r], 0.0f) * wev;
        o += __shfl_xor(o, 1, 64);
        o += __shfl_xor(o, 2, 64);
        o += __shfl_xor(o, 4, 64);
        o += __shfl_xor(o, 8, 64);
        svals[r] = o;
    }
    if (nn == 0) {
#pragma unroll
        for (int r = 0; r < 4; r++) {
            int onS = slot_base + q * 4 + r;
            if (onS < N) out[order[onS]] = 1.0f / (1.0f + __expf(-svals[r]));
        }
    }
}

extern "C" void kernel_launch(void* const* d_in, const int* in_sizes, int n_in,
                              void* d_out, int out_size, void* d_ws, size_t ws_size,
                              hipStream_t stream) {
    const float* x    = (const float*)d_in[0];
    const int*   ei   = (const int*)d_in[1];
    const float* w    = (const float*)d_in[2];
    const float* W1   = (const float*)d_in[3];
    const float* b1   = (const float*)d_in[4];
    const float* W2   = (const float*)d_in[5];
    const float* b2   = (const float*)d_in[6];
    const float* Wend = (const float*)d_in[7];
    float* out = (float*)d_out;

    const int N = in_sizes[0] / 2;   // 500000
    const int E = in_sizes[2];       // 4000000
    const int NB = (N + BW - 1) / BW;  // 245

    const int* src = ei;
    const int* dst = ei + E;

    // workspace layout: binCount 4KB | payload 26.1MB | seg 2MB | dinv2 2MB |
    // rdinv 2MB | order 2MB | inv 2MB | zbuf 8MB (z0..z3) | g0 16MB |
    // ubuf 64MB (u0..u3); binBuf (34.1MB) aliased over u1..u3 (48MB; dead
    // after build)
    int*      binCount = (int*)d_ws;
    unsigned* payload  = (unsigned*)(binCount + 1024);
    int*      seg      = (int*)(payload + (size_t)NB * CAP);
    float*    dinv2    = (float*)(seg + N);
    float*    rdinv    = dinv2 + N;
    int*      order    = (int*)(rdinv + N);
    int*      inv      = order + N;
    __half2*  zbuf     = (__half2*)(inv + N);
    __half*   g0       = (__half*)(zbuf + (size_t)4 * N);
    __half*   ubuf     = g0 + (size_t)16 * N;
    uint2*    binBuf   = (uint2*)(ubuf + (size_t)16 * N);   // over u1..u3

    const int gE_bin = (E + BIN_CHUNK - 1) / BIN_CHUNK;   // 245
    const int gN   = (N + TB - 1) / TB;                   // 1954
    const int gN4  = (4 * N + TB - 1) / TB;               // 7813
    const int gFin = (N + 63) / 64;                       // 7813 (64 slots/block)
    const int nquads = NB * (CAP / 4);
    const int gRemap = (nquads + TB - 1) / TB;

    hipMemsetAsync(binCount, 0, 1024 * sizeof(int), stream);

    // CSR build (slot-sorted) + payload src remap to slot space
    bin_kernel<<<gE_bin, TBIN, 0, stream>>>(src, dst, w, binCount, binBuf, E, NB);
    build_kernel<<<NB, TBLD, 0, stream>>>(binCount, binBuf, payload, seg, dinv2, rdinv,
                                          order, inv, x, zbuf, N, NB);
    remap_kernel<<<gRemap, TB, 0, stream>>>((uint4*)payload, inv, nquads, N);

    // conv1 hops (C=2): z1..z3, then fused z4+epilogue
    for (int k = 1; k <= 3; k++) {
        hop2_kernel<<<gN, TB, 0, stream>>>(seg, payload, zbuf + (size_t)(k - 1) * N,
                                           dinv2, zbuf + (size_t)k * N, N);
    }
    hop2_final_kernel<<<gN, TB, 0, stream>>>(seg, payload, zbuf, x, order, rdinv, dinv2,
                                             W1, b1, g0, ubuf, N);

    // conv2 hops (C=16): u1..u3 (4 thr/slot), then fused u4+MFMA epilogue
    for (int k = 1; k <= 3; k++) {
        hop16_kernel<<<gN4, TB, 0, stream>>>(seg, payload, ubuf + (size_t)(k - 1) * 16 * N,
                                             dinv2, ubuf + (size_t)k * 16 * N, N);
    }
    hop16_final_kernel<<<gFin, TB, 0, stream>>>(seg, payload, g0, ubuf, order, rdinv, dinv2,
                                                W2, b2, Wend, out, N);
}

// Round 2
// 553.759 us; speedup vs baseline: 1.0854x; 1.0854x over previous
//
#include <hip/hip_runtime.h>
#include <hip/hip_fp16.h>
#include <math.h>

// ---------------------------------------------------------------------------
// TAGConv x2 + linear + sigmoid, 500k nodes / 4M edges.
// Round 16: revert R15 slot-sort (regressed: masked gather lanes never cost
// memory concurrency; remap/order machinery was pure overhead). R14 base +
// dual-stream interior hop16: each thread serves slot s AND s+N/2 with
// interleaved payload/gather chains -> 2x per-lane loads in flight. Probes
// latency-vs-fabric bound for the conv2 gather.
// Scaled-state propagation z_k = dinv .* h_k (fp16 state); MFMA epilogue;
// LDS counting-sort build (R13); paired-group gathers (R14).
// ---------------------------------------------------------------------------

#define TB 256
#define TBLD 1024
#define TBIN 1024
#define BSHIFT 11
#define BW 2048             // nodes per bucket
#define CAPB 17408          // binBuf cap (raw recs; mean 16384, ~8 sigma)
#define CAP 26624           // payload cap per bucket (8-padded; mean ~23.6k)
#define HALF_CAP 13312      // ord staging per node-half
#define BIN_CHUNK 16384     // edges per block in bin_kernel
#define WQ 8191.0f          // 13-bit weight quantization

typedef _Float16 half8 __attribute__((ext_vector_type(8)));
typedef float floatx4 __attribute__((ext_vector_type(4)));

// Phase 1: one-pass binning, register-staged dst. rec: {src|ld<<19, w-bits}
__global__ __launch_bounds__(TBIN) void bin_kernel(
        const int* __restrict__ src, const int* __restrict__ dst,
        const float* __restrict__ w, int* __restrict__ binCount,
        uint2* __restrict__ binBuf, int E, int NB) {
    __shared__ int bcnt[256];
    __shared__ int bbase[256];
    for (int i = threadIdx.x; i < 256; i += TBIN) bcnt[i] = 0;
    __syncthreads();

    int base = blockIdx.x * BIN_CHUNK;
    int d[16];
#pragma unroll
    for (int j = 0; j < 16; j++) {
        int e = base + threadIdx.x + j * TBIN;
        d[j] = (e < E) ? dst[e] : -1;
        if (d[j] >= 0) atomicAdd(&bcnt[d[j] >> BSHIFT], 1);
    }
    __syncthreads();
    for (int i = threadIdx.x; i < NB; i += TBIN) {
        int c = bcnt[i];
        bbase[i] = c ? atomicAdd(&binCount[i], c) : 0;
        bcnt[i] = 0;   // reuse as local cursor
    }
    __syncthreads();
#pragma unroll
    for (int j = 0; j < 16; j++) {
        if (d[j] >= 0) {
            int e = base + threadIdx.x + j * TBIN;
            int b = d[j] >> BSHIFT;
            int off = bbase[b] + atomicAdd(&bcnt[b], 1);
            if (off < CAPB) {
                binBuf[(size_t)b * CAPB + off] =
                    make_uint2((unsigned)src[e] | ((unsigned)(d[j] & (BW - 1)) << 19),
                               __float_as_uint(w[e]));
            }
        }
    }
}

// Phase 2: one block per bucket. Count -> scan (8-padded) -> per-node outs ->
// for each 1024-node half: LDS counting-sort index, then coalesced payload
// stream-out (pads = 0 records).
__global__ __launch_bounds__(TBLD) void build_kernel(
        const int* __restrict__ binCount, const uint2* __restrict__ binBuf,
        unsigned* __restrict__ payload, int* __restrict__ seg,
        float* __restrict__ dinv2, float* __restrict__ rdinv,
        const float* __restrict__ x, __half2* __restrict__ z0,
        int N, int NB) {
    __shared__ int   cnt[BW];
    __shared__ float wsum[BW];
    __shared__ int   start[BW];
    __shared__ unsigned short ord[HALF_CAP];
    __shared__ int   tmp[TBLD];
    __shared__ int   stot;
    int b = blockIdx.x;
    int nBase = b << BSHIFT;
    int nCount = min(BW, N - nBase);
    int m = min(binCount[b], CAPB);

    for (int i = threadIdx.x; i < BW; i += TBLD) { cnt[i] = 0; wsum[i] = 0.0f; }
    __syncthreads();

    const uint2* recs = binBuf + (size_t)b * CAPB;
    for (int i = threadIdx.x; i < m; i += TBLD) {
        uint2 r = recs[i];
        int ld = r.x >> 19;
        atomicAdd(&cnt[ld], 1);
        atomicAdd(&wsum[ld], __uint_as_float(r.y));
    }
    __syncthreads();

    // exclusive scan of 8-padded counts, 2 elems/thread
    int b2i = threadIdx.x * 2;
    int c0 = (cnt[b2i] + 7) & ~7;
    int c1 = (cnt[b2i + 1] + 7) & ~7;
    int s = c0 + c1;
    tmp[threadIdx.x] = s;
    __syncthreads();
    for (int off = 1; off < TBLD; off <<= 1) {
        int t = (threadIdx.x >= off) ? tmp[threadIdx.x - off] : 0;
        __syncthreads();
        tmp[threadIdx.x] += t;
        __syncthreads();
    }
    int run = tmp[threadIdx.x] - s;
    start[b2i] = run;
    start[b2i + 1] = run + c0;
    if (threadIdx.x == TBLD - 1) stot = run + s;   // total padded size
    __syncthreads();

    int tot = min(stot, CAP);
    int mid = (nCount > 1024) ? min(start[1024], CAP) : tot;

    // per-node outputs
    for (int i = threadIdx.x; i < nCount; i += TBLD) {
        int n = nBase + i;
        int cc = cnt[i];
        int st = start[i];
        int ng = (cc + 7) >> 3;
        if (st >= CAP) { ng = 0; }
        else if (st + 8 * ng > CAP) { ng = (CAP - st) >> 3; }
        seg[n] = (st >> 3) | (ng << 16);
        float dsum = wsum[i];
        float di = (dsum > 0.0f) ? rsqrtf(dsum) : 0.0f;
        dinv2[n] = di * di;
        rdinv[n] = dsum * di;            // sqrt(deg), 0 if deg==0
        float2 xv = reinterpret_cast<const float2*>(x)[n];
        z0[n] = __float22half2_rn(make_float2(di * xv.x, di * xv.y));
    }
    __syncthreads();

    size_t pbase = (size_t)b * CAP;
    for (int half = 0; half < 2; half++) {
        int lo = half << 10, hi = lo + 1024;
        int pbeg = half ? mid : 0;
        int pend = half ? tot : mid;
        int limit = pend - pbeg;
        int limc = min(limit, HALF_CAP);

        // cursors (reuse cnt) + ord init
        for (int i = lo + threadIdx.x; i < hi; i += TBLD) cnt[i] = start[i] - pbeg;
        for (int j = threadIdx.x; j < limc; j += TBLD) ord[j] = 0xFFFF;
        __syncthreads();

        // counting-sort index pass
        for (int i = threadIdx.x; i < m; i += TBLD) {
            uint2 r = recs[i];
            int ld = r.x >> 19;
            if (ld >= lo && ld < hi) {
                int pos = atomicAdd(&cnt[ld], 1);
                if ((unsigned)pos < (unsigned)limc) ord[pos] = (unsigned short)i;
            }
        }
        __syncthreads();

        // coalesced stream-out (random reads hit L2-resident recs)
        for (int j = threadIdx.x; j < limc; j += TBLD) {
            unsigned short oi = ord[j];
            unsigned word = 0;
            if (oi != 0xFFFF) {
                uint2 r = recs[oi];
                unsigned q = (unsigned)__float2int_rn(__uint_as_float(r.y) * WQ);
                word = (r.x & 0x7FFFFu) | (q << 19);
            }
            payload[pbase + pbeg + j] = word;
        }
        for (int j = limc + threadIdx.x; j < limit; j += TBLD)
            payload[pbase + pbeg + j] = 0;
        __syncthreads();
    }
}

// ---- gather helpers: full groups of 8, paired-group MLP, no masks ---------

// C=2
__device__ __forceinline__ void gacc2m(const unsigned* __restrict__ payload,
                                       const __half2* __restrict__ zin,
                                       int beg, int ng, float& ax, float& ay) {
    int g = 0;
    for (; g + 2 <= ng; g += 2, beg += 16) {
        uint4 r0 = *reinterpret_cast<const uint4*>(payload + beg);
        uint4 r1 = *reinterpret_cast<const uint4*>(payload + beg + 4);
        uint4 r2 = *reinterpret_cast<const uint4*>(payload + beg + 8);
        uint4 r3 = *reinterpret_cast<const uint4*>(payload + beg + 12);
        unsigned r[16] = {r0.x, r0.y, r0.z, r0.w, r1.x, r1.y, r1.z, r1.w,
                          r2.x, r2.y, r2.z, r2.w, r3.x, r3.y, r3.z, r3.w};
        __half2 v[16];
#pragma unroll
        for (int j = 0; j < 16; j++) v[j] = zin[r[j] & 0x7FFFFu];
#pragma unroll
        for (int j = 0; j < 16; j++) {
            float wv = (float)(r[j] >> 19) * (1.0f / WQ);
            float2 f = __half22float2(v[j]);
            ax += wv * f.x;
            ay += wv * f.y;
        }
    }
    if (g < ng) {
        uint4 r0 = *reinterpret_cast<const uint4*>(payload + beg);
        uint4 r1 = *reinterpret_cast<const uint4*>(payload + beg + 4);
        unsigned r[8] = {r0.x, r0.y, r0.z, r0.w, r1.x, r1.y, r1.z, r1.w};
        __half2 v[8];
#pragma unroll
        for (int j = 0; j < 8; j++) v[j] = zin[r[j] & 0x7FFFFu];
#pragma unroll
        for (int j = 0; j < 8; j++) {
            float wv = (float)(r[j] >> 19) * (1.0f / WQ);
            float2 f = __half22float2(v[j]);
            ax += wv * f.x;
            ay += wv * f.y;
        }
    }
}

// C=4 (quarter-row); ubase = uin + 4*quarter.
__device__ __forceinline__ void gacc4(const unsigned* __restrict__ payload,
                                      const __half* __restrict__ ubase,
                                      int beg, int ng, float* __restrict__ h) {
    int g = 0;
    for (; g + 2 <= ng; g += 2, beg += 16) {
        uint4 r0 = *reinterpret_cast<const uint4*>(payload + beg);
        uint4 r1 = *reinterpret_cast<const uint4*>(payload + beg + 4);
        uint4 r2 = *reinterpret_cast<const uint4*>(payload + beg + 8);
        uint4 r3 = *reinterpret_cast<const uint4*>(payload + beg + 12);
        unsigned r[16] = {r0.x, r0.y, r0.z, r0.w, r1.x, r1.y, r1.z, r1.w,
                          r2.x, r2.y, r2.z, r2.w, r3.x, r3.y, r3.z, r3.w};
        float2 a[16];
#pragma unroll
        for (int j = 0; j < 16; j++)
            a[j] = *reinterpret_cast<const float2*>(ubase + 16LL * (int)(r[j] & 0x7FFFFu));
#pragma unroll
        for (int j = 0; j < 16; j++) {
            float wv = (float)(r[j] >> 19) * (1.0f / WQ);
            const __half2* hp = reinterpret_cast<const __half2*>(&a[j]);
            float2 v0 = __half22float2(hp[0]);
            float2 v1 = __half22float2(hp[1]);
            h[0] += wv * v0.x;
            h[1] += wv * v0.y;
            h[2] += wv * v1.x;
            h[3] += wv * v1.y;
        }
    }
    if (g < ng) {
        uint4 r0 = *reinterpret_cast<const uint4*>(payload + beg);
        uint4 r1 = *reinterpret_cast<const uint4*>(payload + beg + 4);
        unsigned r[8] = {r0.x, r0.y, r0.z, r0.w, r1.x, r1.y, r1.z, r1.w};
        float2 a[8];
#pragma unroll
        for (int j = 0; j < 8; j++)
            a[j] = *reinterpret_cast<const float2*>(ubase + 16LL * (int)(r[j] & 0x7FFFFu));
#pragma unroll
        for (int j = 0; j < 8; j++) {
            float wv = (float)(r[j] >> 19) * (1.0f / WQ);
            const __half2* hp = reinterpret_cast<const __half2*>(&a[j]);
            float2 v0 = __half22float2(hp[0]);
            float2 v1 = __half22float2(hp[1]);
            h[0] += wv * v0.x;
            h[1] += wv * v0.y;
            h[2] += wv * v1.x;
            h[3] += wv * v1.y;
        }
    }
}

// Dual-stream C=4: two independent payload->gather chains per thread.
// Masked-off groups load a zero payload quad -> wv=0, gather row 0 (L2-hot),
// FMA adds exact 0. Doubles per-lane loads in flight.
__device__ __forceinline__ void gacc4_dual(const unsigned* __restrict__ payload,
                                           const __half* __restrict__ ubase,
                                           int begA, int ngA, int begB, int ngB,
                                           float* __restrict__ hA, float* __restrict__ hB) {
    const uint4 z4 = make_uint4(0u, 0u, 0u, 0u);
    int ngM = (ngA > ngB) ? ngA : ngB;
    for (int g = 0; g < ngM; g++, begA += 8, begB += 8) {
        bool dA = g < ngA, dB = g < ngB;
        uint4 pa0 = dA ? *reinterpret_cast<const uint4*>(payload + begA) : z4;
        uint4 pa1 = dA ? *reinterpret_cast<const uint4*>(payload + begA + 4) : z4;
        uint4 pb0 = dB ? *reinterpret_cast<const uint4*>(payload + begB) : z4;
        uint4 pb1 = dB ? *reinterpret_cast<const uint4*>(payload + begB + 4) : z4;
        unsigned ra[8] = {pa0.x, pa0.y, pa0.z, pa0.w, pa1.x, pa1.y, pa1.z, pa1.w};
        unsigned rb[8] = {pb0.x, pb0.y, pb0.z, pb0.w, pb1.x, pb1.y, pb1.z, pb1.w};
        float2 va[8], vb[8];
#pragma unroll
        for (int j = 0; j < 8; j++)
            va[j] = *reinterpret_cast<const float2*>(ubase + 16LL * (int)(ra[j] & 0x7FFFFu));
#pragma unroll
        for (int j = 0; j < 8; j++)
            vb[j] = *reinterpret_cast<const float2*>(ubase + 16LL * (int)(rb[j] & 0x7FFFFu));
#pragma unroll
        for (int j = 0; j < 8; j++) {
            float wv = (float)(ra[j] >> 19) * (1.0f / WQ);
            const __half2* hp = reinterpret_cast<const __half2*>(&va[j]);
            float2 v0 = __half22float2(hp[0]);
            float2 v1 = __half22float2(hp[1]);
            hA[0] += wv * v0.x;
            hA[1] += wv * v0.y;
            hA[2] += wv * v1.x;
            hA[3] += wv * v1.y;
        }
#pragma unroll
        for (int j = 0; j < 8; j++) {
            float wv = (float)(rb[j] >> 19) * (1.0f / WQ);
            const __half2* hp = reinterpret_cast<const __half2*>(&vb[j]);
            float2 v0 = __half22float2(hp[0]);
            float2 v1 = __half22float2(hp[1]);
            hB[0] += wv * v0.x;
            hB[1] += wv * v0.y;
            hB[2] += wv * v1.x;
            hB[3] += wv * v1.y;
        }
    }
}

// ----------------------------------------------------------------------------

// z_k[n] = dinv2[n] * sum w * z_{k-1}[src]   (C=2, fp16 state), k=1..3
__global__ void hop2_kernel(const int* __restrict__ seg, const unsigned* __restrict__ payload,
                            const __half2* __restrict__ zin, const float* __restrict__ dinv2,
                            __half2* __restrict__ zout, int N) {
    int n = blockIdx.x * TB + threadIdx.x;
    if (n >= N) return;
    int sp = seg[n];
    int beg = (n >> BSHIFT) * CAP + ((sp & 0xFFFF) << 3);
    int ng = sp >> 16;
    float ax = 0.0f, ay = 0.0f;
    gacc2m(payload, zin, beg, ng, ax, ay);
    float sc = dinv2[n];
    zout[n] = __float22half2_rn(make_float2(ax * sc, ay * sc));
}

// Fused hop2 k=4 + conv1 epilogue
__global__ void hop2_final_kernel(const int* __restrict__ seg, const unsigned* __restrict__ payload,
                                  const __half2* __restrict__ zbuf,   // z0..z3
                                  const float* __restrict__ x,
                                  const float* __restrict__ rdinv, const float* __restrict__ dinv2,
                                  const float* __restrict__ W1, const float* __restrict__ b1,
                                  __half* __restrict__ g0, __half* __restrict__ u0, int N) {
    __shared__ float Ws[160];
    __shared__ float bs[16];
    for (int i = threadIdx.x; i < 160; i += blockDim.x) Ws[i] = W1[i];
    if (threadIdx.x < 16) bs[threadIdx.x] = b1[threadIdx.x];
    __syncthreads();

    int n = blockIdx.x * TB + threadIdx.x;
    if (n >= N) return;

    int sp = seg[n];
    int beg = (n >> BSHIFT) * CAP + ((sp & 0xFFFF) << 3);
    int ng = sp >> 16;
    const __half2* z3 = zbuf + (size_t)3 * N;
    float ax = 0.0f, ay = 0.0f;
    gacc2m(payload, z3, beg, ng, ax, ay);
    float sc = dinv2[n];
    float rd = rdinv[n];

    float coeff[10];
    {
        float2 v = reinterpret_cast<const float2*>(x)[n];
        coeff[0] = v.x; coeff[1] = v.y;
    }
#pragma unroll
    for (int k = 1; k <= 3; k++) {
        float2 v = __half22float2(zbuf[(size_t)k * N + n]);
        coeff[2 * k + 0] = rd * v.x;
        coeff[2 * k + 1] = rd * v.y;
    }
    coeff[8] = rd * sc * ax;
    coeff[9] = rd * sc * ay;

    float o[16];
#pragma unroll
    for (int c = 0; c < 16; c++) o[c] = bs[c];
#pragma unroll
    for (int j = 0; j < 10; j++) {
        float cf = coeff[j];
#pragma unroll
        for (int c = 0; c < 16; c++) o[c] += cf * Ws[j * 16 + c];
    }
#pragma unroll
    for (int c = 0; c < 16; c++) o[c] = fmaxf(o[c], 0.0f);

    float di = sc * rd;   // = dinv (0 for deg-0 nodes)

    __half2 gp[8], up[8];
#pragma unroll
    for (int q = 0; q < 8; q++) {
        gp[q] = __float22half2_rn(make_float2(o[2 * q], o[2 * q + 1]));
        up[q] = __float22half2_rn(make_float2(di * o[2 * q], di * o[2 * q + 1]));
    }
    float4* gw = reinterpret_cast<float4*>(g0 + 16LL * n);
    gw[0] = *reinterpret_cast<float4*>(&gp[0]);
    gw[1] = *reinterpret_cast<float4*>(&gp[4]);
    float4* uw = reinterpret_cast<float4*>(u0 + 16LL * n);
    uw[0] = *reinterpret_cast<float4*>(&up[0]);
    uw[1] = *reinterpret_cast<float4*>(&up[4]);
}

// u_k = dinv2 * sum w * u_{k-1}[src]; 4 threads per node (4 channels each),
// dual-stream: thread serves node sA and sA+H (H = ceil(N/2)).
__global__ void hop16_kernel(const int* __restrict__ seg, const unsigned* __restrict__ payload,
                             const __half* __restrict__ uin, const float* __restrict__ dinv2,
                             __half* __restrict__ uout, int N, int H) {
    int gid = blockIdx.x * TB + threadIdx.x;
    int sA = gid >> 2, quarter = gid & 3;
    if (sA >= H) return;
    int sB = sA + H;
    bool hasB = (sB < N);

    int spA = seg[sA];
    int begA = (sA >> BSHIFT) * CAP + ((spA & 0xFFFF) << 3);
    int ngA = spA >> 16;
    int spB = hasB ? seg[sB] : 0;
    int begB = hasB ? ((sB >> BSHIFT) * CAP + ((spB & 0xFFFF) << 3)) : 0;
    int ngB = hasB ? (spB >> 16) : 0;

    float hA[4] = {0.0f, 0.0f, 0.0f, 0.0f};
    float hB[4] = {0.0f, 0.0f, 0.0f, 0.0f};
    gacc4_dual(payload, uin + 4 * quarter, begA, ngA, begB, ngB, hA, hB);

    {
        float sc = dinv2[sA];
        __half2 p[2];
        p[0] = __float22half2_rn(make_float2(hA[0] * sc, hA[1] * sc));
        p[1] = __float22half2_rn(make_float2(hA[2] * sc, hA[3] * sc));
        *reinterpret_cast<float2*>(uout + 16LL * sA + 4 * quarter) = *reinterpret_cast<float2*>(&p[0]);
    }
    if (hasB) {
        float sc = dinv2[sB];
        __half2 p[2];
        p[0] = __float22half2_rn(make_float2(hB[0] * sc, hB[1] * sc));
        p[1] = __float22half2_rn(make_float2(hB[2] * sc, hB[3] * sc));
        *reinterpret_cast<float2*>(uout + 16LL * sB + 4 * quarter) = *reinterpret_cast<float2*>(&p[0]);
    }
}

// Fused hop16 k=4 + conv2 epilogue via MFMA + endLinear + sigmoid.
// Wave = 16 nodes x 4 quads; node=lane&15, quarter=lane>>4.
__global__ void hop16_final_kernel(const int* __restrict__ seg, const unsigned* __restrict__ payload,
                                   const __half* __restrict__ g0, const __half* __restrict__ ubuf,
                                   const float* __restrict__ rdinv, const float* __restrict__ dinv2,
                                   const float* __restrict__ W2, const float* __restrict__ b2,
                                   const float* __restrict__ Wend, float* __restrict__ out, int N) {
    int lane = threadIdx.x & 63;
    int wave = threadIdx.x >> 6;
    int q = lane >> 4;           // quad -> K-chunk
    int nn = lane & 15;          // node row m / output column n
    int node_base = (blockIdx.x * 4 + wave) * 16;
    int node = node_base + nn;
    int nodec = min(node, N - 1);

    // B fragments: lane supplies B[K=32t+8q+i][n=nn] from W2 (fp32->fp16)
    half8 bf[3];
#pragma unroll
    for (int t = 0; t < 3; t++) {
        half8 bv;
#pragma unroll
        for (int i = 0; i < 8; i++) {
            int K = 32 * t + 8 * q + i;
            K = (K < 80) ? K : 79;          // pad rows never used (A=0 there)
            bv[i] = (_Float16)W2[K * 16 + nn];
        }
        bf[t] = bv;
    }
    float bsv = b2[nn];
    float wev = Wend[nn];

    // gather k=4 term: h = quarter q (channels 4q..4q+3) of node's u4 row
    int sp = seg[nodec];
    int beg = (nodec >> BSHIFT) * CAP + ((sp & 0xFFFF) << 3);
    int ng = sp >> 16;
    const __half* u3 = ubuf + (size_t)3 * 16 * N;
    float h[4] = {0.0f, 0.0f, 0.0f, 0.0f};
    gacc4(payload, u3 + 4 * q, beg, ng, h);

    float rd = rdinv[nodec];
    float sc = dinv2[nodec];

    // A fragment t=0: q0,q1 -> g0 (raw); q2,q3 -> u1 (x rd)
    const __half* a0p = ((q < 2) ? g0 : (ubuf + (size_t)16 * N)) + 16LL * nodec + 8 * (q & 1);
    half8 a0 = *reinterpret_cast<const half8*>(a0p);
    a0 = a0 * ((q >= 2) ? (_Float16)rd : (_Float16)1.0f);

    // A fragment t=1: q0,q1 -> u2; q2,q3 -> u3 (all x rd)
    const __half* a1p = ((q < 2) ? (ubuf + (size_t)2 * 16 * N) : (ubuf + (size_t)3 * 16 * N))
                        + 16LL * nodec + 8 * (q & 1);
    half8 a1 = *reinterpret_cast<const half8*>(a1p);
    a1 = a1 * (_Float16)rd;

    // A fragment t=2: q0,q1 -> h (x rd*sc) via shfl repack; q2,q3 -> zero pad
    float s4 = rd * sc;
    __half2 hh0 = __floats2half2_rn(h[0] * s4, h[1] * s4);
    __half2 hh1 = __floats2half2_rn(h[2] * s4, h[3] * s4);
    int p0, p1;
    p0 = *reinterpret_cast<int*>(&hh0);
    p1 = *reinterpret_cast<int*>(&hh1);
    int srcA = (nn + (q << 5)) & 63;   // q0: quarters 0,1 ; q1: quarters 2,3
    int srcB = (srcA + 16) & 63;
    int lo0 = __shfl(p0, srcA, 64);
    int lo1 = __shfl(p1, srcA, 64);
    int hi0 = __shfl(p0, srcB, 64);
    int hi1 = __shfl(p1, srcB, 64);
    if (q >= 2) { lo0 = 0; lo1 = 0; hi0 = 0; hi1 = 0; }
    union { half8 v; int u[4]; } a2;
    a2.u[0] = lo0; a2.u[1] = lo1; a2.u[2] = hi0; a2.u[3] = hi1;

    floatx4 acc = {bsv, bsv, bsv, bsv};
    acc = __builtin_amdgcn_mfma_f32_16x16x32_f16(a0, bf[0], acc, 0, 0, 0);
    acc = __builtin_amdgcn_mfma_f32_16x16x32_f16(a1, bf[1], acc, 0, 0, 0);
    acc = __builtin_amdgcn_mfma_f32_16x16x32_f16(a2.v, bf[2], acc, 0, 0, 0);

    // D[m = q*4+reg][n = nn]: relu, dot with Wend over n, sigmoid, store
    float svals[4];
#pragma unroll
    for (int r = 0; r < 4; r++) {
        float o = fmaxf(acc[r], 0.0f) * wev;
        o += __shfl_xor(o, 1, 64);
        o += __shfl_xor(o, 2, 64);
        o += __shfl_xor(o, 4, 64);
        o += __shfl_xor(o, 8, 64);
        svals[r] = o;
    }
    if (nn == 0) {
#pragma unroll
        for (int r = 0; r < 4; r++) {
            int on = node_base + q * 4 + r;
            if (on < N) out[on] = 1.0f / (1.0f + __expf(-svals[r]));
        }
    }
}

extern "C" void kernel_launch(void* const* d_in, const int* in_sizes, int n_in,
                              void* d_out, int out_size, void* d_ws, size_t ws_size,
                              hipStream_t stream) {
    const float* x    = (const float*)d_in[0];
    const int*   ei   = (const int*)d_in[1];
    const float* w    = (const float*)d_in[2];
    const float* W1   = (const float*)d_in[3];
    const float* b1   = (const float*)d_in[4];
    const float* W2   = (const float*)d_in[5];
    const float* b2   = (const float*)d_in[6];
    const float* Wend = (const float*)d_in[7];
    float* out = (float*)d_out;

    const int N = in_sizes[0] / 2;   // 500000
    const int E = in_sizes[2];       // 4000000
    const int NB = (N + BW - 1) / BW;  // 245

    const int* src = ei;
    const int* dst = ei + E;

    // workspace layout: binCount 4KB | payload 26.1MB | seg 2MB | dinv2 2MB |
    // rdinv 2MB | zbuf 8MB (z0..z3) | g0 16MB | ubuf 64MB (u0..u3);
    // binBuf (34.1MB) aliased over u1..u3 (48MB; dead after build)
    int*      binCount = (int*)d_ws;
    unsigned* payload  = (unsigned*)(binCount + 1024);
    int*      seg      = (int*)(payload + (size_t)NB * CAP);
    float*    dinv2    = (float*)(seg + N);
    float*    rdinv    = dinv2 + N;
    __half2*  zbuf     = (__half2*)(rdinv + N);
    __half*   g0       = (__half*)(zbuf + (size_t)4 * N);
    __half*   ubuf     = g0 + (size_t)16 * N;
    uint2*    binBuf   = (uint2*)(ubuf + (size_t)16 * N);   // over u1..u3

    const int gE_bin = (E + BIN_CHUNK - 1) / BIN_CHUNK;   // 245
    const int gN   = (N + TB - 1) / TB;                   // 1954
    const int H    = (N + 1) / 2;                         // 250000
    const int gN4h = (4 * H + TB - 1) / TB;               // 3907
    const int gFin = (N + 63) / 64;                       // 7813 (64 nodes/block)

    hipMemsetAsync(binCount, 0, 1024 * sizeof(int), stream);

    // CSR build
    bin_kernel<<<gE_bin, TBIN, 0, stream>>>(src, dst, w, binCount, binBuf, E, NB);
    build_kernel<<<NB, TBLD, 0, stream>>>(binCount, binBuf, payload, seg, dinv2, rdinv, x, zbuf, N, NB);

    // conv1 hops (C=2): z1..z3, then fused z4+epilogue
    for (int k = 1; k <= 3; k++) {
        hop2_kernel<<<gN, TB, 0, stream>>>(seg, payload, zbuf + (size_t)(k - 1) * N,
                                           dinv2, zbuf + (size_t)k * N, N);
    }
    hop2_final_kernel<<<gN, TB, 0, stream>>>(seg, payload, zbuf, x, rdinv, dinv2,
                                             W1, b1, g0, ubuf, N);

    // conv2 hops (C=16): u1..u3 (4 thr/node, dual-stream), then fused u4+MFMA epilogue
    for (int k = 1; k <= 3; k++) {
        hop16_kernel<<<gN4h, TB, 0, stream>>>(seg, payload, ubuf + (size_t)(k - 1) * 16 * N,
                                              dinv2, ubuf + (size_t)k * 16 * N, N, H);
    }
    hop16_final_kernel<<<gFin, TB, 0, stream>>>(seg, payload, g0, ubuf, rdinv, dinv2,
                                                W2, b2, Wend, out, N);
}

// Round 4
// 549.857 us; speedup vs baseline: 1.0931x; 1.0071x over previous
//
#include <hip/hip_runtime.h>
#include <hip/hip_fp16.h>
#include <math.h>

// ---------------------------------------------------------------------------
// TAGConv x2 + linear + sigmoid, 500k nodes / 4M edges.
// Round 18: resubmit of R17 (bench infra failed; no data). Exact R14 base
// (best: 545.6us) + halved VMEM request count in interior hop16:
// 2 lanes/node x dwordx4 (16B) instead of 4 lanes x dwordx2 (8B). Same
// 64B lines touched; tests TA/L2-port vs DRAM-line-service as the limiter.
// R15 (slot-sort) and R16 (dual-stream) were null -> gather is not
// latency-bound.
// Scaled-state propagation z_k = dinv .* h_k (fp16 state); MFMA epilogue;
// LDS counting-sort build (R13); paired-group gathers (R14).
// ---------------------------------------------------------------------------

#define TB 256
#define TBLD 1024
#define TBIN 1024
#define BSHIFT 11
#define BW 2048             // nodes per bucket
#define CAPB 17408          // binBuf cap (raw recs; mean 16384, ~8 sigma)
#define CAP 26624           // payload cap per bucket (8-padded; mean ~23.6k)
#define HALF_CAP 13312      // ord staging per node-half
#define BIN_CHUNK 16384     // edges per block in bin_kernel
#define WQ 8191.0f          // 13-bit weight quantization

typedef _Float16 half8 __attribute__((ext_vector_type(8)));
typedef float floatx4 __attribute__((ext_vector_type(4)));

// Phase 1: one-pass binning, register-staged dst. rec: {src|ld<<19, w-bits}
__global__ __launch_bounds__(TBIN) void bin_kernel(
        const int* __restrict__ src, const int* __restrict__ dst,
        const float* __restrict__ w, int* __restrict__ binCount,
        uint2* __restrict__ binBuf, int E, int NB) {
    __shared__ int bcnt[256];
    __shared__ int bbase[256];
    for (int i = threadIdx.x; i < 256; i += TBIN) bcnt[i] = 0;
    __syncthreads();

    int base = blockIdx.x * BIN_CHUNK;
    int d[16];
#pragma unroll
    for (int j = 0; j < 16; j++) {
        int e = base + threadIdx.x + j * TBIN;
        d[j] = (e < E) ? dst[e] : -1;
        if (d[j] >= 0) atomicAdd(&bcnt[d[j] >> BSHIFT], 1);
    }
    __syncthreads();
    for (int i = threadIdx.x; i < NB; i += TBIN) {
        int c = bcnt[i];
        bbase[i] = c ? atomicAdd(&binCount[i], c) : 0;
        bcnt[i] = 0;   // reuse as local cursor
    }
    __syncthreads();
#pragma unroll
    for (int j = 0; j < 16; j++) {
        if (d[j] >= 0) {
            int e = base + threadIdx.x + j * TBIN;
            int b = d[j] >> BSHIFT;
            int off = bbase[b] + atomicAdd(&bcnt[b], 1);
            if (off < CAPB) {
                binBuf[(size_t)b * CAPB + off] =
                    make_uint2((unsigned)src[e] | ((unsigned)(d[j] & (BW - 1)) << 19),
                               __float_as_uint(w[e]));
            }
        }
    }
}

// Phase 2: one block per bucket. Count -> scan (8-padded) -> per-node outs ->
// for each 1024-node half: LDS counting-sort index, then coalesced payload
// stream-out (pads = 0 records).
__global__ __launch_bounds__(TBLD) void build_kernel(
        const int* __restrict__ binCount, const uint2* __restrict__ binBuf,
        unsigned* __restrict__ payload, int* __restrict__ seg,
        float* __restrict__ dinv2, float* __restrict__ rdinv,
        const float* __restrict__ x, __half2* __restrict__ z0,
        int N, int NB) {
    __shared__ int   cnt[BW];
    __shared__ float wsum[BW];
    __shared__ int   start[BW];
    __shared__ unsigned short ord[HALF_CAP];
    __shared__ int   tmp[TBLD];
    __shared__ int   stot;
    int b = blockIdx.x;
    int nBase = b << BSHIFT;
    int nCount = min(BW, N - nBase);
    int m = min(binCount[b], CAPB);

    for (int i = threadIdx.x; i < BW; i += TBLD) { cnt[i] = 0; wsum[i] = 0.0f; }
    __syncthreads();

    const uint2* recs = binBuf + (size_t)b * CAPB;
    for (int i = threadIdx.x; i < m; i += TBLD) {
        uint2 r = recs[i];
        int ld = r.x >> 19;
        atomicAdd(&cnt[ld], 1);
        atomicAdd(&wsum[ld], __uint_as_float(r.y));
    }
    __syncthreads();

    // exclusive scan of 8-padded counts, 2 elems/thread
    int b2i = threadIdx.x * 2;
    int c0 = (cnt[b2i] + 7) & ~7;
    int c1 = (cnt[b2i + 1] + 7) & ~7;
    int s = c0 + c1;
    tmp[threadIdx.x] = s;
    __syncthreads();
    for (int off = 1; off < TBLD; off <<= 1) {
        int t = (threadIdx.x >= off) ? tmp[threadIdx.x - off] : 0;
        __syncthreads();
        tmp[threadIdx.x] += t;
        __syncthreads();
    }
    int run = tmp[threadIdx.x] - s;
    start[b2i] = run;
    start[b2i + 1] = run + c0;
    if (threadIdx.x == TBLD - 1) stot = run + s;   // total padded size
    __syncthreads();

    int tot = min(stot, CAP);
    int mid = (nCount > 1024) ? min(start[1024], CAP) : tot;

    // per-node outputs
    for (int i = threadIdx.x; i < nCount; i += TBLD) {
        int n = nBase + i;
        int cc = cnt[i];
        int st = start[i];
        int ng = (cc + 7) >> 3;
        if (st >= CAP) { ng = 0; }
        else if (st + 8 * ng > CAP) { ng = (CAP - st) >> 3; }
        seg[n] = (st >> 3) | (ng << 16);
        float dsum = wsum[i];
        float di = (dsum > 0.0f) ? rsqrtf(dsum) : 0.0f;
        dinv2[n] = di * di;
        rdinv[n] = dsum * di;            // sqrt(deg), 0 if deg==0
        float2 xv = reinterpret_cast<const float2*>(x)[n];
        z0[n] = __float22half2_rn(make_float2(di * xv.x, di * xv.y));
    }
    __syncthreads();

    size_t pbase = (size_t)b * CAP;
    for (int half = 0; half < 2; half++) {
        int lo = half << 10, hi = lo + 1024;
        int pbeg = half ? mid : 0;
        int pend = half ? tot : mid;
        int limit = pend - pbeg;
        int limc = min(limit, HALF_CAP);

        // cursors (reuse cnt) + ord init
        for (int i = lo + threadIdx.x; i < hi; i += TBLD) cnt[i] = start[i] - pbeg;
        for (int j = threadIdx.x; j < limc; j += TBLD) ord[j] = 0xFFFF;
        __syncthreads();

        // counting-sort index pass
        for (int i = threadIdx.x; i < m; i += TBLD) {
            uint2 r = recs[i];
            int ld = r.x >> 19;
            if (ld >= lo && ld < hi) {
                int pos = atomicAdd(&cnt[ld], 1);
                if ((unsigned)pos < (unsigned)limc) ord[pos] = (unsigned short)i;
            }
        }
        __syncthreads();

        // coalesced stream-out (random reads hit L2-resident recs)
        for (int j = threadIdx.x; j < limc; j += TBLD) {
            unsigned short oi = ord[j];
            unsigned word = 0;
            if (oi != 0xFFFF) {
                uint2 r = recs[oi];
                unsigned q = (unsigned)__float2int_rn(__uint_as_float(r.y) * WQ);
                word = (r.x & 0x7FFFFu) | (q << 19);
            }
            payload[pbase + pbeg + j] = word;
        }
        for (int j = limc + threadIdx.x; j < limit; j += TBLD)
            payload[pbase + pbeg + j] = 0;
        __syncthreads();
    }
}

// ---- gather helpers: full groups of 8, paired-group MLP, no masks ---------

// C=2
__device__ __forceinline__ void gacc2m(const unsigned* __restrict__ payload,
                                       const __half2* __restrict__ zin,
                                       int beg, int ng, float& ax, float& ay) {
    int g = 0;
    for (; g + 2 <= ng; g += 2, beg += 16) {
        uint4 r0 = *reinterpret_cast<const uint4*>(payload + beg);
        uint4 r1 = *reinterpret_cast<const uint4*>(payload + beg + 4);
        uint4 r2 = *reinterpret_cast<const uint4*>(payload + beg + 8);
        uint4 r3 = *reinterpret_cast<const uint4*>(payload + beg + 12);
        unsigned r[16] = {r0.x, r0.y, r0.z, r0.w, r1.x, r1.y, r1.z, r1.w,
                          r2.x, r2.y, r2.z, r2.w, r3.x, r3.y, r3.z, r3.w};
        __half2 v[16];
#pragma unroll
        for (int j = 0; j < 16; j++) v[j] = zin[r[j] & 0x7FFFFu];
#pragma unroll
        for (int j = 0; j < 16; j++) {
            float wv = (float)(r[j] >> 19) * (1.0f / WQ);
            float2 f = __half22float2(v[j]);
            ax += wv * f.x;
            ay += wv * f.y;
        }
    }
    if (g < ng) {
        uint4 r0 = *reinterpret_cast<const uint4*>(payload + beg);
        uint4 r1 = *reinterpret_cast<const uint4*>(payload + beg + 4);
        unsigned r[8] = {r0.x, r0.y, r0.z, r0.w, r1.x, r1.y, r1.z, r1.w};
        __half2 v[8];
#pragma unroll
        for (int j = 0; j < 8; j++) v[j] = zin[r[j] & 0x7FFFFu];
#pragma unroll
        for (int j = 0; j < 8; j++) {
            float wv = (float)(r[j] >> 19) * (1.0f / WQ);
            float2 f = __half22float2(v[j]);
            ax += wv * f.x;
            ay += wv * f.y;
        }
    }
}

// C=4 (quarter-row); ubase = uin + 4*quarter.  (used by hop16_final)
__device__ __forceinline__ void gacc4(const unsigned* __restrict__ payload,
                                      const __half* __restrict__ ubase,
                                      int beg, int ng, float* __restrict__ h) {
    int g = 0;
    for (; g + 2 <= ng; g += 2, beg += 16) {
        uint4 r0 = *reinterpret_cast<const uint4*>(payload + beg);
        uint4 r1 = *reinterpret_cast<const uint4*>(payload + beg + 4);
        uint4 r2 = *reinterpret_cast<const uint4*>(payload + beg + 8);
        uint4 r3 = *reinterpret_cast<const uint4*>(payload + beg + 12);
        unsigned r[16] = {r0.x, r0.y, r0.z, r0.w, r1.x, r1.y, r1.z, r1.w,
                          r2.x, r2.y, r2.z, r2.w, r3.x, r3.y, r3.z, r3.w};
        float2 a[16];
#pragma unroll
        for (int j = 0; j < 16; j++)
            a[j] = *reinterpret_cast<const float2*>(ubase + 16LL * (int)(r[j] & 0x7FFFFu));
#pragma unroll
        for (int j = 0; j < 16; j++) {
            float wv = (float)(r[j] >> 19) * (1.0f / WQ);
            const __half2* hp = reinterpret_cast<const __half2*>(&a[j]);
            float2 v0 = __half22float2(hp[0]);
            float2 v1 = __half22float2(hp[1]);
            h[0] += wv * v0.x;
            h[1] += wv * v0.y;
            h[2] += wv * v1.x;
            h[3] += wv * v1.y;
        }
    }
    if (g < ng) {
        uint4 r0 = *reinterpret_cast<const uint4*>(payload + beg);
        uint4 r1 = *reinterpret_cast<const uint4*>(payload + beg + 4);
        unsigned r[8] = {r0.x, r0.y, r0.z, r0.w, r1.x, r1.y, r1.z, r1.w};
        float2 a[8];
#pragma unroll
        for (int j = 0; j < 8; j++)
            a[j] = *reinterpret_cast<const float2*>(ubase + 16LL * (int)(r[j] & 0x7FFFFu));
#pragma unroll
        for (int j = 0; j < 8; j++) {
            float wv = (float)(r[j] >> 19) * (1.0f / WQ);
            const __half2* hp = reinterpret_cast<const __half2*>(&a[j]);
            float2 v0 = __half22float2(hp[0]);
            float2 v1 = __half22float2(hp[1]);
            h[0] += wv * v0.x;
            h[1] += wv * v0.y;
            h[2] += wv * v1.x;
            h[3] += wv * v1.y;
        }
    }
}

// C=8 (half-row, dwordx4 gathers); ubase = uin + 8*half. Same edge order per
// channel as the 4-lane version -> bitwise-identical sums.
__device__ __forceinline__ void gacc8(const unsigned* __restrict__ payload,
                                      const __half* __restrict__ ubase,
                                      int beg, int ng, float* __restrict__ h) {
    int g = 0;
    for (; g + 2 <= ng; g += 2, beg += 16) {
        uint4 r0 = *reinterpret_cast<const uint4*>(payload + beg);
        uint4 r1 = *reinterpret_cast<const uint4*>(payload + beg + 4);
        uint4 r2 = *reinterpret_cast<const uint4*>(payload + beg + 8);
        uint4 r3 = *reinterpret_cast<const uint4*>(payload + beg + 12);
        unsigned r[16] = {r0.x, r0.y, r0.z, r0.w, r1.x, r1.y, r1.z, r1.w,
                          r2.x, r2.y, r2.z, r2.w, r3.x, r3.y, r3.z, r3.w};
        float4 a[16];
#pragma unroll
        for (int j = 0; j < 16; j++)
            a[j] = *reinterpret_cast<const float4*>(ubase + 16LL * (int)(r[j] & 0x7FFFFu));
#pragma unroll
        for (int j = 0; j < 16; j++) {
            float wv = (float)(r[j] >> 19) * (1.0f / WQ);
            const __half2* hp = reinterpret_cast<const __half2*>(&a[j]);
            float2 v0 = __half22float2(hp[0]);
            float2 v1 = __half22float2(hp[1]);
            float2 v2 = __half22float2(hp[2]);
            float2 v3 = __half22float2(hp[3]);
            h[0] += wv * v0.x;  h[1] += wv * v0.y;
            h[2] += wv * v1.x;  h[3] += wv * v1.y;
            h[4] += wv * v2.x;  h[5] += wv * v2.y;
            h[6] += wv * v3.x;  h[7] += wv * v3.y;
        }
    }
    if (g < ng) {
        uint4 r0 = *reinterpret_cast<const uint4*>(payload + beg);
        uint4 r1 = *reinterpret_cast<const uint4*>(payload + beg + 4);
        unsigned r[8] = {r0.x, r0.y, r0.z, r0.w, r1.x, r1.y, r1.z, r1.w};
        float4 a[8];
#pragma unroll
        for (int j = 0; j < 8; j++)
            a[j] = *reinterpret_cast<const float4*>(ubase + 16LL * (int)(r[j] & 0x7FFFFu));
#pragma unroll
        for (int j = 0; j < 8; j++) {
            float wv = (float)(r[j] >> 19) * (1.0f / WQ);
            const __half2* hp = reinterpret_cast<const __half2*>(&a[j]);
            float2 v0 = __half22float2(hp[0]);
            float2 v1 = __half22float2(hp[1]);
            float2 v2 = __half22float2(hp[2]);
            float2 v3 = __half22float2(hp[3]);
            h[0] += wv * v0.x;  h[1] += wv * v0.y;
            h[2] += wv * v1.x;  h[3] += wv * v1.y;
            h[4] += wv * v2.x;  h[5] += wv * v2.y;
            h[6] += wv * v3.x;  h[7] += wv * v3.y;
        }
    }
}

// ----------------------------------------------------------------------------

// z_k[n] = dinv2[n] * sum w * z_{k-1}[src]   (C=2, fp16 state), k=1..3
__global__ void hop2_kernel(const int* __restrict__ seg, const unsigned* __restrict__ payload,
                            const __half2* __restrict__ zin, const float* __restrict__ dinv2,
                            __half2* __restrict__ zout, int N) {
    int n = blockIdx.x * TB + threadIdx.x;
    if (n >= N) return;
    int sp = seg[n];
    int beg = (n >> BSHIFT) * CAP + ((sp & 0xFFFF) << 3);
    int ng = sp >> 16;
    float ax = 0.0f, ay = 0.0f;
    gacc2m(payload, zin, beg, ng, ax, ay);
    float sc = dinv2[n];
    zout[n] = __float22half2_rn(make_float2(ax * sc, ay * sc));
}

// Fused hop2 k=4 + conv1 epilogue
__global__ void hop2_final_kernel(const int* __restrict__ seg, const unsigned* __restrict__ payload,
                                  const __half2* __restrict__ zbuf,   // z0..z3
                                  const float* __restrict__ x,
                                  const float* __restrict__ rdinv, const float* __restrict__ dinv2,
                                  const float* __restrict__ W1, const float* __restrict__ b1,
                                  __half* __restrict__ g0, __half* __restrict__ u0, int N) {
    __shared__ float Ws[160];
    __shared__ float bs[16];
    for (int i = threadIdx.x; i < 160; i += blockDim.x) Ws[i] = W1[i];
    if (threadIdx.x < 16) bs[threadIdx.x] = b1[threadIdx.x];
    __syncthreads();

    int n = blockIdx.x * TB + threadIdx.x;
    if (n >= N) return;

    int sp = seg[n];
    int beg = (n >> BSHIFT) * CAP + ((sp & 0xFFFF) << 3);
    int ng = sp >> 16;
    const __half2* z3 = zbuf + (size_t)3 * N;
    float ax = 0.0f, ay = 0.0f;
    gacc2m(payload, z3, beg, ng, ax, ay);
    float sc = dinv2[n];
    float rd = rdinv[n];

    float coeff[10];
    {
        float2 v = reinterpret_cast<const float2*>(x)[n];
        coeff[0] = v.x; coeff[1] = v.y;
    }
#pragma unroll
    for (int k = 1; k <= 3; k++) {
        float2 v = __half22float2(zbuf[(size_t)k * N + n]);
        coeff[2 * k + 0] = rd * v.x;
        coeff[2 * k + 1] = rd * v.y;
    }
    coeff[8] = rd * sc * ax;
    coeff[9] = rd * sc * ay;

    float o[16];
#pragma unroll
    for (int c = 0; c < 16; c++) o[c] = bs[c];
#pragma unroll
    for (int j = 0; j < 10; j++) {
        float cf = coeff[j];
#pragma unroll
        for (int c = 0; c < 16; c++) o[c] += cf * Ws[j * 16 + c];
    }
#pragma unroll
    for (int c = 0; c < 16; c++) o[c] = fmaxf(o[c], 0.0f);

    float di = sc * rd;   // = dinv (0 for deg-0 nodes)

    __half2 gp[8], up[8];
#pragma unroll
    for (int q = 0; q < 8; q++) {
        gp[q] = __float22half2_rn(make_float2(o[2 * q], o[2 * q + 1]));
        up[q] = __float22half2_rn(make_float2(di * o[2 * q], di * o[2 * q + 1]));
    }
    float4* gw = reinterpret_cast<float4*>(g0 + 16LL * n);
    gw[0] = *reinterpret_cast<float4*>(&gp[0]);
    gw[1] = *reinterpret_cast<float4*>(&gp[4]);
    float4* uw = reinterpret_cast<float4*>(u0 + 16LL * n);
    uw[0] = *reinterpret_cast<float4*>(&up[0]);
    uw[1] = *reinterpret_cast<float4*>(&up[4]);
}

// u_k = dinv2 * sum w * u_{k-1}[src]; 2 threads per node (8 channels each),
// dwordx4 gathers -> half the VMEM requests of the 4-lane version.
__global__ void hop16_kernel(const int* __restrict__ seg, const unsigned* __restrict__ payload,
                             const __half* __restrict__ uin, const float* __restrict__ dinv2,
                             __half* __restrict__ uout, int N) {
    int gid = blockIdx.x * TB + threadIdx.x;
    int n = gid >> 1, half = gid & 1;
    if (n >= N) return;
    int sp = seg[n];
    int beg = (n >> BSHIFT) * CAP + ((sp & 0xFFFF) << 3);
    int ng = sp >> 16;

    float h[8] = {0.0f, 0.0f, 0.0f, 0.0f, 0.0f, 0.0f, 0.0f, 0.0f};
    gacc8(payload, uin + 8 * half, beg, ng, h);

    float sc = dinv2[n];
    __half2 p[4];
#pragma unroll
    for (int q = 0; q < 4; q++)
        p[q] = __float22half2_rn(make_float2(h[2 * q] * sc, h[2 * q + 1] * sc));
    *reinterpret_cast<float4*>(uout + 16LL * n + 8 * half) = *reinterpret_cast<float4*>(&p[0]);
}

// Fused hop16 k=4 + conv2 epilogue via MFMA + endLinear + sigmoid.
// Wave = 16 nodes x 4 quads; node=lane&15, quarter=lane>>4.
__global__ void hop16_final_kernel(const int* __restrict__ seg, const unsigned* __restrict__ payload,
                                   const __half* __restrict__ g0, const __half* __restrict__ ubuf,
                                   const float* __restrict__ rdinv, const float* __restrict__ dinv2,
                                   const float* __restrict__ W2, const float* __restrict__ b2,
                                   const float* __restrict__ Wend, float* __restrict__ out, int N) {
    int lane = threadIdx.x & 63;
    int wave = threadIdx.x >> 6;
    int q = lane >> 4;           // quad -> K-chunk
    int nn = lane & 15;          // node row m / output column n
    int node_base = (blockIdx.x * 4 + wave) * 16;
    int node = node_base + nn;
    int nodec = min(node, N - 1);

    // B fragments: lane supplies B[K=32t+8q+i][n=nn] from W2 (fp32->fp16)
    half8 bf[3];
#pragma unroll
    for (int t = 0; t < 3; t++) {
        half8 bv;
#pragma unroll
        for (int i = 0; i < 8; i++) {
            int K = 32 * t + 8 * q + i;
            K = (K < 80) ? K : 79;          // pad rows never used (A=0 there)
            bv[i] = (_Float16)W2[K * 16 + nn];
        }
        bf[t] = bv;
    }
    float bsv = b2[nn];
    float wev = Wend[nn];

    // gather k=4 term: h = quarter q (channels 4q..4q+3) of node's u4 row
    int sp = seg[nodec];
    int beg = (nodec >> BSHIFT) * CAP + ((sp & 0xFFFF) << 3);
    int ng = sp >> 16;
    const __half* u3 = ubuf + (size_t)3 * 16 * N;
    float h[4] = {0.0f, 0.0f, 0.0f, 0.0f};
    gacc4(payload, u3 + 4 * q, beg, ng, h);

    float rd = rdinv[nodec];
    float sc = dinv2[nodec];

    // A fragment t=0: q0,q1 -> g0 (raw); q2,q3 -> u1 (x rd)
    const __half* a0p = ((q < 2) ? g0 : (ubuf + (size_t)16 * N)) + 16LL * nodec + 8 * (q & 1);
    half8 a0 = *reinterpret_cast<const half8*>(a0p);
    a0 = a0 * ((q >= 2) ? (_Float16)rd : (_Float16)1.0f);

    // A fragment t=1: q0,q1 -> u2; q2,q3 -> u3 (all x rd)
    const __half* a1p = ((q < 2) ? (ubuf + (size_t)2 * 16 * N) : (ubuf + (size_t)3 * 16 * N))
                        + 16LL * nodec + 8 * (q & 1);
    half8 a1 = *reinterpret_cast<const half8*>(a1p);
    a1 = a1 * (_Float16)rd;

    // A fragment t=2: q0,q1 -> h (x rd*sc) via shfl repack; q2,q3 -> zero pad
    float s4 = rd * sc;
    __half2 hh0 = __floats2half2_rn(h[0] * s4, h[1] * s4);
    __half2 hh1 = __floats2half2_rn(h[2] * s4, h[3] * s4);
    int p0, p1;
    p0 = *reinterpret_cast<int*>(&hh0);
    p1 = *reinterpret_cast<int*>(&hh1);
    int srcA = (nn + (q << 5)) & 63;   // q0: quarters 0,1 ; q1: quarters 2,3
    int srcB = (srcA + 16) & 63;
    int lo0 = __shfl(p0, srcA, 64);
    int lo1 = __shfl(p1, srcA, 64);
    int hi0 = __shfl(p0, srcB, 64);
    int hi1 = __shfl(p1, srcB, 64);
    if (q >= 2) { lo0 = 0; lo1 = 0; hi0 = 0; hi1 = 0; }
    union { half8 v; int u[4]; } a2;
    a2.u[0] = lo0; a2.u[1] = lo1; a2.u[2] = hi0; a2.u[3] = hi1;

    floatx4 acc = {bsv, bsv, bsv, bsv};
    acc = __builtin_amdgcn_mfma_f32_16x16x32_f16(a0, bf[0], acc, 0, 0, 0);
    acc = __builtin_amdgcn_mfma_f32_16x16x32_f16(a1, bf[1], acc, 0, 0, 0);
    acc = __builtin_amdgcn_mfma_f32_16x16x32_f16(a2.v, bf[2], acc, 0, 0, 0);

    // D[m = q*4+reg][n = nn]: relu, dot with Wend over n, sigmoid, store
    float svals[4];
#pragma unroll
    for (int r = 0; r < 4; r++) {
        float o = fmaxf(acc[r], 0.0f) * wev;
        o += __shfl_xor(o, 1, 64);
        o += __shfl_xor(o, 2, 64);
        o += __shfl_xor(o, 4, 64);
        o += __shfl_xor(o, 8, 64);
        svals[r] = o;
    }
    if (nn == 0) {
#pragma unroll
        for (int r = 0; r < 4; r++) {
            int on = node_base + q * 4 + r;
            if (on < N) out[on] = 1.0f / (1.0f + __expf(-svals[r]));
        }
    }
}

extern "C" void kernel_launch(void* const* d_in, const int* in_sizes, int n_in,
                              void* d_out, int out_size, void* d_ws, size_t ws_size,
                              hipStream_t stream) {
    const float* x    = (const float*)d_in[0];
    const int*   ei   = (const int*)d_in[1];
    const float* w    = (const float*)d_in[2];
    const float* W1   = (const float*)d_in[3];
    const float* b1   = (const float*)d_in[4];
    const float* W2   = (const float*)d_in[5];
    const float* b2   = (const float*)d_in[6];
    const float* Wend = (const float*)d_in[7];
    float* out = (float*)d_out;

    const int N = in_sizes[0] / 2;   // 500000
    const int E = in_sizes[2];       // 4000000
    const int NB = (N + BW - 1) / BW;  // 245

    const int* src = ei;
    const int* dst = ei + E;

    // workspace layout: binCount 4KB | payload 26.1MB | seg 2MB | dinv2 2MB |
    // rdinv 2MB | zbuf 8MB (z0..z3) | g0 16MB | ubuf 64MB (u0..u3);
    // binBuf (34.1MB) aliased over u1..u3 (48MB; dead after build)
    int*      binCount = (int*)d_ws;
    unsigned* payload  = (unsigned*)(binCount + 1024);
    int*      seg      = (int*)(payload + (size_t)NB * CAP);
    float*    dinv2    = (float*)(seg + N);
    float*    rdinv    = dinv2 + N;
    __half2*  zbuf     = (__half2*)(rdinv + N);
    __half*   g0       = (__half*)(zbuf + (size_t)4 * N);
    __half*   ubuf     = g0 + (size_t)16 * N;
    uint2*    binBuf   = (uint2*)(ubuf + (size_t)16 * N);   // over u1..u3

    const int gE_bin = (E + BIN_CHUNK - 1) / BIN_CHUNK;   // 245
    const int gN   = (N + TB - 1) / TB;                   // 1954
    const int gN2  = (2 * N + TB - 1) / TB;               // 3907 (2 thr/node)
    const int gFin = (N + 63) / 64;                       // 7813 (64 nodes/block)

    hipMemsetAsync(binCount, 0, 1024 * sizeof(int), stream);

    // CSR build
    bin_kernel<<<gE_bin, TBIN, 0, stream>>>(src, dst, w, binCount, binBuf, E, NB);
    build_kernel<<<NB, TBLD, 0, stream>>>(binCount, binBuf, payload, seg, dinv2, rdinv, x, zbuf, N, NB);

    // conv1 hops (C=2): z1..z3, then fused z4+epilogue
    for (int k = 1; k <= 3; k++) {
        hop2_kernel<<<gN, TB, 0, stream>>>(seg, payload, zbuf + (size_t)(k - 1) * N,
                                           dinv2, zbuf + (size_t)k * N, N);
    }
    hop2_final_kernel<<<gN, TB, 0, stream>>>(seg, payload, zbuf, x, rdinv, dinv2,
                                             W1, b1, g0, ubuf, N);

    // conv2 hops (C=16): u1..u3 (2 thr/node, dwordx4), then fused u4+MFMA epilogue
    for (int k = 1; k <= 3; k++) {
        hop16_kernel<<<gN2, TB, 0, stream>>>(seg, payload, ubuf + (size_t)(k - 1) * 16 * N,
                                             dinv2, ubuf + (size_t)k * 16 * N, N);
    }
    hop16_final_kernel<<<gFin, TB, 0, stream>>>(seg, payload, g0, ubuf, rdinv, dinv2,
                                                W2, b2, Wend, out, N);
}

// Round 5
// 539.060 us; speedup vs baseline: 1.1150x; 1.0200x over previous
//
#include <hip/hip_runtime.h>
#include <hip/hip_fp16.h>
#include <math.h>

// ---------------------------------------------------------------------------
// TAGConv x2 + linear + sigmoid, 500k nodes / 4M edges.
// Round 19: R14 base restored (4-lane interior hop16; R18's request-halving
// was null -> gather is line-service-bound, ~3.55 TB/s, three orthogonal
// probes null). This round: single-pass build_kernel — ord[] sized to the
// FULL bucket (CAP x u16 = 53KB LDS, total ~80KB of the 160KB/CU), removing
// the two half-passes that re-scanned all records and discarded half.
// Scaled-state propagation z_k = dinv .* h_k (fp16 state); MFMA epilogue;
// LDS counting-sort build (R13); paired-group gathers (R14).
// ---------------------------------------------------------------------------

#define TB 256
#define TBLD 1024
#define TBIN 1024
#define BSHIFT 11
#define BW 2048             // nodes per bucket
#define CAPB 17408          // binBuf cap (raw recs; mean 16384, ~8 sigma)
#define CAP 26624           // payload cap per bucket (8-padded; mean ~23.6k)
#define BIN_CHUNK 16384     // edges per block in bin_kernel
#define WQ 8191.0f          // 13-bit weight quantization

typedef _Float16 half8 __attribute__((ext_vector_type(8)));
typedef float floatx4 __attribute__((ext_vector_type(4)));

// Phase 1: one-pass binning, register-staged dst. rec: {src|ld<<19, w-bits}
__global__ __launch_bounds__(TBIN) void bin_kernel(
        const int* __restrict__ src, const int* __restrict__ dst,
        const float* __restrict__ w, int* __restrict__ binCount,
        uint2* __restrict__ binBuf, int E, int NB) {
    __shared__ int bcnt[256];
    __shared__ int bbase[256];
    for (int i = threadIdx.x; i < 256; i += TBIN) bcnt[i] = 0;
    __syncthreads();

    int base = blockIdx.x * BIN_CHUNK;
    int d[16];
#pragma unroll
    for (int j = 0; j < 16; j++) {
        int e = base + threadIdx.x + j * TBIN;
        d[j] = (e < E) ? dst[e] : -1;
        if (d[j] >= 0) atomicAdd(&bcnt[d[j] >> BSHIFT], 1);
    }
    __syncthreads();
    for (int i = threadIdx.x; i < NB; i += TBIN) {
        int c = bcnt[i];
        bbase[i] = c ? atomicAdd(&binCount[i], c) : 0;
        bcnt[i] = 0;   // reuse as local cursor
    }
    __syncthreads();
#pragma unroll
    for (int j = 0; j < 16; j++) {
        if (d[j] >= 0) {
            int e = base + threadIdx.x + j * TBIN;
            int b = d[j] >> BSHIFT;
            int off = bbase[b] + atomicAdd(&bcnt[b], 1);
            if (off < CAPB) {
                binBuf[(size_t)b * CAPB + off] =
                    make_uint2((unsigned)src[e] | ((unsigned)(d[j] & (BW - 1)) << 19),
                               __float_as_uint(w[e]));
            }
        }
    }
}

// Phase 2: one block per bucket. Count -> scan (8-padded) -> per-node outs ->
// SINGLE full-bucket LDS counting-sort index pass, then one coalesced payload
// stream-out (pads = 0 records). ~80KB LDS (of 160KB/CU); 245 blocks on
// 256 CUs -> 1 block/CU either way.
__global__ __launch_bounds__(TBLD) void build_kernel(
        const int* __restrict__ binCount, const uint2* __restrict__ binBuf,
        unsigned* __restrict__ payload, int* __restrict__ seg,
        float* __restrict__ dinv2, float* __restrict__ rdinv,
        const float* __restrict__ x, __half2* __restrict__ z0,
        int N, int NB) {
    __shared__ int   cnt[BW];
    __shared__ float wsum[BW];
    __shared__ int   start[BW];
    __shared__ unsigned short ord[CAP];
    __shared__ int   tmp[TBLD];
    __shared__ int   stot;
    int b = blockIdx.x;
    int nBase = b << BSHIFT;
    int nCount = min(BW, N - nBase);
    int m = min(binCount[b], CAPB);

    for (int i = threadIdx.x; i < BW; i += TBLD) { cnt[i] = 0; wsum[i] = 0.0f; }
    __syncthreads();

    const uint2* recs = binBuf + (size_t)b * CAPB;
    for (int i = threadIdx.x; i < m; i += TBLD) {
        uint2 r = recs[i];
        int ld = r.x >> 19;
        atomicAdd(&cnt[ld], 1);
        atomicAdd(&wsum[ld], __uint_as_float(r.y));
    }
    __syncthreads();

    // exclusive scan of 8-padded counts, 2 elems/thread
    int b2i = threadIdx.x * 2;
    int c0 = (cnt[b2i] + 7) & ~7;
    int c1 = (cnt[b2i + 1] + 7) & ~7;
    int s = c0 + c1;
    tmp[threadIdx.x] = s;
    __syncthreads();
    for (int off = 1; off < TBLD; off <<= 1) {
        int t = (threadIdx.x >= off) ? tmp[threadIdx.x - off] : 0;
        __syncthreads();
        tmp[threadIdx.x] += t;
        __syncthreads();
    }
    int run = tmp[threadIdx.x] - s;
    start[b2i] = run;
    start[b2i + 1] = run + c0;
    if (threadIdx.x == TBLD - 1) stot = run + s;   // total padded size
    __syncthreads();

    int tot = min(stot, CAP);

    // per-node outputs
    for (int i = threadIdx.x; i < nCount; i += TBLD) {
        int n = nBase + i;
        int cc = cnt[i];
        int st = start[i];
        int ng = (cc + 7) >> 3;
        if (st >= CAP) { ng = 0; }
        else if (st + 8 * ng > CAP) { ng = (CAP - st) >> 3; }
        seg[n] = (st >> 3) | (ng << 16);
        float dsum = wsum[i];
        float di = (dsum > 0.0f) ? rsqrtf(dsum) : 0.0f;
        dinv2[n] = di * di;
        rdinv[n] = dsum * di;            // sqrt(deg), 0 if deg==0
        float2 xv = reinterpret_cast<const float2*>(x)[n];
        z0[n] = __float22half2_rn(make_float2(di * xv.x, di * xv.y));
    }
    __syncthreads();

    // cursors (reuse cnt) + ord init over the full bucket
    for (int i = threadIdx.x; i < nCount; i += TBLD) cnt[i] = start[i];
    for (int j = threadIdx.x; j < tot; j += TBLD) ord[j] = 0xFFFF;
    __syncthreads();

    // single counting-sort index pass
    for (int i = threadIdx.x; i < m; i += TBLD) {
        uint2 r = recs[i];
        int ld = r.x >> 19;
        int pos = atomicAdd(&cnt[ld], 1);
        if ((unsigned)pos < (unsigned)tot) ord[pos] = (unsigned short)i;
    }
    __syncthreads();

    // coalesced stream-out (random reads hit L2-resident recs)
    size_t pbase = (size_t)b * CAP;
    for (int j = threadIdx.x; j < tot; j += TBLD) {
        unsigned short oi = ord[j];
        unsigned word = 0;
        if (oi != 0xFFFF) {
            uint2 r = recs[oi];
            unsigned q = (unsigned)__float2int_rn(__uint_as_float(r.y) * WQ);
            word = (r.x & 0x7FFFFu) | (q << 19);
        }
        payload[pbase + j] = word;
    }
}

// ---- gather helpers: full groups of 8, paired-group MLP, no masks ---------

// C=2
__device__ __forceinline__ void gacc2m(const unsigned* __restrict__ payload,
                                       const __half2* __restrict__ zin,
                                       int beg, int ng, float& ax, float& ay) {
    int g = 0;
    for (; g + 2 <= ng; g += 2, beg += 16) {
        uint4 r0 = *reinterpret_cast<const uint4*>(payload + beg);
        uint4 r1 = *reinterpret_cast<const uint4*>(payload + beg + 4);
        uint4 r2 = *reinterpret_cast<const uint4*>(payload + beg + 8);
        uint4 r3 = *reinterpret_cast<const uint4*>(payload + beg + 12);
        unsigned r[16] = {r0.x, r0.y, r0.z, r0.w, r1.x, r1.y, r1.z, r1.w,
                          r2.x, r2.y, r2.z, r2.w, r3.x, r3.y, r3.z, r3.w};
        __half2 v[16];
#pragma unroll
        for (int j = 0; j < 16; j++) v[j] = zin[r[j] & 0x7FFFFu];
#pragma unroll
        for (int j = 0; j < 16; j++) {
            float wv = (float)(r[j] >> 19) * (1.0f / WQ);
            float2 f = __half22float2(v[j]);
            ax += wv * f.x;
            ay += wv * f.y;
        }
    }
    if (g < ng) {
        uint4 r0 = *reinterpret_cast<const uint4*>(payload + beg);
        uint4 r1 = *reinterpret_cast<const uint4*>(payload + beg + 4);
        unsigned r[8] = {r0.x, r0.y, r0.z, r0.w, r1.x, r1.y, r1.z, r1.w};
        __half2 v[8];
#pragma unroll
        for (int j = 0; j < 8; j++) v[j] = zin[r[j] & 0x7FFFFu];
#pragma unroll
        for (int j = 0; j < 8; j++) {
            float wv = (float)(r[j] >> 19) * (1.0f / WQ);
            float2 f = __half22float2(v[j]);
            ax += wv * f.x;
            ay += wv * f.y;
        }
    }
}

// C=4 (quarter-row); ubase = uin + 4*quarter.
__device__ __forceinline__ void gacc4(const unsigned* __restrict__ payload,
                                      const __half* __restrict__ ubase,
                                      int beg, int ng, float* __restrict__ h) {
    int g = 0;
    for (; g + 2 <= ng; g += 2, beg += 16) {
        uint4 r0 = *reinterpret_cast<const uint4*>(payload + beg);
        uint4 r1 = *reinterpret_cast<const uint4*>(payload + beg + 4);
        uint4 r2 = *reinterpret_cast<const uint4*>(payload + beg + 8);
        uint4 r3 = *reinterpret_cast<const uint4*>(payload + beg + 12);
        unsigned r[16] = {r0.x, r0.y, r0.z, r0.w, r1.x, r1.y, r1.z, r1.w,
                          r2.x, r2.y, r2.z, r2.w, r3.x, r3.y, r3.z, r3.w};
        float2 a[16];
#pragma unroll
        for (int j = 0; j < 16; j++)
            a[j] = *reinterpret_cast<const float2*>(ubase + 16LL * (int)(r[j] & 0x7FFFFu));
#pragma unroll
        for (int j = 0; j < 16; j++) {
            float wv = (float)(r[j] >> 19) * (1.0f / WQ);
            const __half2* hp = reinterpret_cast<const __half2*>(&a[j]);
            float2 v0 = __half22float2(hp[0]);
            float2 v1 = __half22float2(hp[1]);
            h[0] += wv * v0.x;
            h[1] += wv * v0.y;
            h[2] += wv * v1.x;
            h[3] += wv * v1.y;
        }
    }
    if (g < ng) {
        uint4 r0 = *reinterpret_cast<const uint4*>(payload + beg);
        uint4 r1 = *reinterpret_cast<const uint4*>(payload + beg + 4);
        unsigned r[8] = {r0.x, r0.y, r0.z, r0.w, r1.x, r1.y, r1.z, r1.w};
        float2 a[8];
#pragma unroll
        for (int j = 0; j < 8; j++)
            a[j] = *reinterpret_cast<const float2*>(ubase + 16LL * (int)(r[j] & 0x7FFFFu));
#pragma unroll
        for (int j = 0; j < 8; j++) {
            float wv = (float)(r[j] >> 19) * (1.0f / WQ);
            const __half2* hp = reinterpret_cast<const __half2*>(&a[j]);
            float2 v0 = __half22float2(hp[0]);
            float2 v1 = __half22float2(hp[1]);
            h[0] += wv * v0.x;
            h[1] += wv * v0.y;
            h[2] += wv * v1.x;
            h[3] += wv * v1.y;
        }
    }
}

// ----------------------------------------------------------------------------

// z_k[n] = dinv2[n] * sum w * z_{k-1}[src]   (C=2, fp16 state), k=1..3
__global__ void hop2_kernel(const int* __restrict__ seg, const unsigned* __restrict__ payload,
                            const __half2* __restrict__ zin, const float* __restrict__ dinv2,
                            __half2* __restrict__ zout, int N) {
    int n = blockIdx.x * TB + threadIdx.x;
    if (n >= N) return;
    int sp = seg[n];
    int beg = (n >> BSHIFT) * CAP + ((sp & 0xFFFF) << 3);
    int ng = sp >> 16;
    float ax = 0.0f, ay = 0.0f;
    gacc2m(payload, zin, beg, ng, ax, ay);
    float sc = dinv2[n];
    zout[n] = __float22half2_rn(make_float2(ax * sc, ay * sc));
}

// Fused hop2 k=4 + conv1 epilogue
__global__ void hop2_final_kernel(const int* __restrict__ seg, const unsigned* __restrict__ payload,
                                  const __half2* __restrict__ zbuf,   // z0..z3
                                  const float* __restrict__ x,
                                  const float* __restrict__ rdinv, const float* __restrict__ dinv2,
                                  const float* __restrict__ W1, const float* __restrict__ b1,
                                  __half* __restrict__ g0, __half* __restrict__ u0, int N) {
    __shared__ float Ws[160];
    __shared__ float bs[16];
    for (int i = threadIdx.x; i < 160; i += blockDim.x) Ws[i] = W1[i];
    if (threadIdx.x < 16) bs[threadIdx.x] = b1[threadIdx.x];
    __syncthreads();

    int n = blockIdx.x * TB + threadIdx.x;
    if (n >= N) return;

    int sp = seg[n];
    int beg = (n >> BSHIFT) * CAP + ((sp & 0xFFFF) << 3);
    int ng = sp >> 16;
    const __half2* z3 = zbuf + (size_t)3 * N;
    float ax = 0.0f, ay = 0.0f;
    gacc2m(payload, z3, beg, ng, ax, ay);
    float sc = dinv2[n];
    float rd = rdinv[n];

    float coeff[10];
    {
        float2 v = reinterpret_cast<const float2*>(x)[n];
        coeff[0] = v.x; coeff[1] = v.y;
    }
#pragma unroll
    for (int k = 1; k <= 3; k++) {
        float2 v = __half22float2(zbuf[(size_t)k * N + n]);
        coeff[2 * k + 0] = rd * v.x;
        coeff[2 * k + 1] = rd * v.y;
    }
    coeff[8] = rd * sc * ax;
    coeff[9] = rd * sc * ay;

    float o[16];
#pragma unroll
    for (int c = 0; c < 16; c++) o[c] = bs[c];
#pragma unroll
    for (int j = 0; j < 10; j++) {
        float cf = coeff[j];
#pragma unroll
        for (int c = 0; c < 16; c++) o[c] += cf * Ws[j * 16 + c];
    }
#pragma unroll
    for (int c = 0; c < 16; c++) o[c] = fmaxf(o[c], 0.0f);

    float di = sc * rd;   // = dinv (0 for deg-0 nodes)

    __half2 gp[8], up[8];
#pragma unroll
    for (int q = 0; q < 8; q++) {
        gp[q] = __float22half2_rn(make_float2(o[2 * q], o[2 * q + 1]));
        up[q] = __float22half2_rn(make_float2(di * o[2 * q], di * o[2 * q + 1]));
    }
    float4* gw = reinterpret_cast<float4*>(g0 + 16LL * n);
    gw[0] = *reinterpret_cast<float4*>(&gp[0]);
    gw[1] = *reinterpret_cast<float4*>(&gp[4]);
    float4* uw = reinterpret_cast<float4*>(u0 + 16LL * n);
    uw[0] = *reinterpret_cast<float4*>(&up[0]);
    uw[1] = *reinterpret_cast<float4*>(&up[4]);
}

// u_k = dinv2 * sum w * u_{k-1}[src]; 4 threads per node (4 channels each)
__global__ void hop16_kernel(const int* __restrict__ seg, const unsigned* __restrict__ payload,
                             const __half* __restrict__ uin, const float* __restrict__ dinv2,
                             __half* __restrict__ uout, int N) {
    int gid = blockIdx.x * TB + threadIdx.x;
    int n = gid >> 2, quarter = gid & 3;
    if (n >= N) return;
    int sp = seg[n];
    int beg = (n >> BSHIFT) * CAP + ((sp & 0xFFFF) << 3);
    int ng = sp >> 16;

    float h[4] = {0.0f, 0.0f, 0.0f, 0.0f};
    gacc4(payload, uin + 4 * quarter, beg, ng, h);

    float sc = dinv2[n];
    __half2 p[2];
    p[0] = __float22half2_rn(make_float2(h[0] * sc, h[1] * sc));
    p[1] = __float22half2_rn(make_float2(h[2] * sc, h[3] * sc));
    *reinterpret_cast<float2*>(uout + 16LL * n + 4 * quarter) = *reinterpret_cast<float2*>(&p[0]);
}

// Fused hop16 k=4 + conv2 epilogue via MFMA + endLinear + sigmoid.
// Wave = 16 nodes x 4 quads; node=lane&15, quarter=lane>>4.
__global__ void hop16_final_kernel(const int* __restrict__ seg, const unsigned* __restrict__ payload,
                                   const __half* __restrict__ g0, const __half* __restrict__ ubuf,
                                   const float* __restrict__ rdinv, const float* __restrict__ dinv2,
                                   const float* __restrict__ W2, const float* __restrict__ b2,
                                   const float* __restrict__ Wend, float* __restrict__ out, int N) {
    int lane = threadIdx.x & 63;
    int wave = threadIdx.x >> 6;
    int q = lane >> 4;           // quad -> K-chunk
    int nn = lane & 15;          // node row m / output column n
    int node_base = (blockIdx.x * 4 + wave) * 16;
    int node = node_base + nn;
    int nodec = min(node, N - 1);

    // B fragments: lane supplies B[K=32t+8q+i][n=nn] from W2 (fp32->fp16)
    half8 bf[3];
#pragma unroll
    for (int t = 0; t < 3; t++) {
        half8 bv;
#pragma unroll
        for (int i = 0; i < 8; i++) {
            int K = 32 * t + 8 * q + i;
            K = (K < 80) ? K : 79;          // pad rows never used (A=0 there)
            bv[i] = (_Float16)W2[K * 16 + nn];
        }
        bf[t] = bv;
    }
    float bsv = b2[nn];
    float wev = Wend[nn];

    // gather k=4 term: h = quarter q (channels 4q..4q+3) of node's u4 row
    int sp = seg[nodec];
    int beg = (nodec >> BSHIFT) * CAP + ((sp & 0xFFFF) << 3);
    int ng = sp >> 16;
    const __half* u3 = ubuf + (size_t)3 * 16 * N;
    float h[4] = {0.0f, 0.0f, 0.0f, 0.0f};
    gacc4(payload, u3 + 4 * q, beg, ng, h);

    float rd = rdinv[nodec];
    float sc = dinv2[nodec];

    // A fragment t=0: q0,q1 -> g0 (raw); q2,q3 -> u1 (x rd)
    const __half* a0p = ((q < 2) ? g0 : (ubuf + (size_t)16 * N)) + 16LL * nodec + 8 * (q & 1);
    half8 a0 = *reinterpret_cast<const half8*>(a0p);
    a0 = a0 * ((q >= 2) ? (_Float16)rd : (_Float16)1.0f);

    // A fragment t=1: q0,q1 -> u2; q2,q3 -> u3 (all x rd)
    const __half* a1p = ((q < 2) ? (ubuf + (size_t)2 * 16 * N) : (ubuf + (size_t)3 * 16 * N))
                        + 16LL * nodec + 8 * (q & 1);
    half8 a1 = *reinterpret_cast<const half8*>(a1p);
    a1 = a1 * (_Float16)rd;

    // A fragment t=2: q0,q1 -> h (x rd*sc) via shfl repack; q2,q3 -> zero pad
    float s4 = rd * sc;
    __half2 hh0 = __floats2half2_rn(h[0] * s4, h[1] * s4);
    __half2 hh1 = __floats2half2_rn(h[2] * s4, h[3] * s4);
    int p0, p1;
    p0 = *reinterpret_cast<int*>(&hh0);
    p1 = *reinterpret_cast<int*>(&hh1);
    int srcA = (nn + (q << 5)) & 63;   // q0: quarters 0,1 ; q1: quarters 2,3
    int srcB = (srcA + 16) & 63;
    int lo0 = __shfl(p0, srcA, 64);
    int lo1 = __shfl(p1, srcA, 64);
    int hi0 = __shfl(p0, srcB, 64);
    int hi1 = __shfl(p1, srcB, 64);
    if (q >= 2) { lo0 = 0; lo1 = 0; hi0 = 0; hi1 = 0; }
    union { half8 v; int u[4]; } a2;
    a2.u[0] = lo0; a2.u[1] = lo1; a2.u[2] = hi0; a2.u[3] = hi1;

    floatx4 acc = {bsv, bsv, bsv, bsv};
    acc = __builtin_amdgcn_mfma_f32_16x16x32_f16(a0, bf[0], acc, 0, 0, 0);
    acc = __builtin_amdgcn_mfma_f32_16x16x32_f16(a1, bf[1], acc, 0, 0, 0);
    acc = __builtin_amdgcn_mfma_f32_16x16x32_f16(a2.v, bf[2], acc, 0, 0, 0);

    // D[m = q*4+reg][n = nn]: relu, dot with Wend over n, sigmoid, store
    float svals[4];
#pragma unroll
    for (int r = 0; r < 4; r++) {
        float o = fmaxf(acc[r], 0.0f) * wev;
        o += __shfl_xor(o, 1, 64);
        o += __shfl_xor(o, 2, 64);
        o += __shfl_xor(o, 4, 64);
        o += __shfl_xor(o, 8, 64);
        svals[r] = o;
    }
    if (nn == 0) {
#pragma unroll
        for (int r = 0; r < 4; r++) {
            int on = node_base + q * 4 + r;
            if (on < N) out[on] = 1.0f / (1.0f + __expf(-svals[r]));
        }
    }
}

extern "C" void kernel_launch(void* const* d_in, const int* in_sizes, int n_in,
                              void* d_out, int out_size, void* d_ws, size_t ws_size,
                              hipStream_t stream) {
    const float* x    = (const float*)d_in[0];
    const int*   ei   = (const int*)d_in[1];
    const float* w    = (const float*)d_in[2];
    const float* W1   = (const float*)d_in[3];
    const float* b1   = (const float*)d_in[4];
    const float* W2   = (const float*)d_in[5];
    const float* b2   = (const float*)d_in[6];
    const float* Wend = (const float*)d_in[7];
    float* out = (float*)d_out;

    const int N = in_sizes[0] / 2;   // 500000
    const int E = in_sizes[2];       // 4000000
    const int NB = (N + BW - 1) / BW;  // 245

    const int* src = ei;
    const int* dst = ei + E;

    // workspace layout: binCount 4KB | payload 26.1MB | seg 2MB | dinv2 2MB |
    // rdinv 2MB | zbuf 8MB (z0..z3) | g0 16MB | ubuf 64MB (u0..u3);
    // binBuf (34.1MB) aliased over u1..u3 (48MB; dead after build)
    int*      binCount = (int*)d_ws;
    unsigned* payload  = (unsigned*)(binCount + 1024);
    int*      seg      = (int*)(payload + (size_t)NB * CAP);
    float*    dinv2    = (float*)(seg + N);
    float*    rdinv    = dinv2 + N;
    __half2*  zbuf     = (__half2*)(rdinv + N);
    __half*   g0       = (__half*)(zbuf + (size_t)4 * N);
    __half*   ubuf     = g0 + (size_t)16 * N;
    uint2*    binBuf   = (uint2*)(ubuf + (size_t)16 * N);   // over u1..u3

    const int gE_bin = (E + BIN_CHUNK - 1) / BIN_CHUNK;   // 245
    const int gN   = (N + TB - 1) / TB;                   // 1954
    const int gN4  = (4 * N + TB - 1) / TB;               // 7813
    const int gFin = (N + 63) / 64;                       // 7813 (64 nodes/block)

    hipMemsetAsync(binCount, 0, 1024 * sizeof(int), stream);

    // CSR build
    bin_kernel<<<gE_bin, TBIN, 0, stream>>>(src, dst, w, binCount, binBuf, E, NB);
    build_kernel<<<NB, TBLD, 0, stream>>>(binCount, binBuf, payload, seg, dinv2, rdinv, x, zbuf, N, NB);

    // conv1 hops (C=2): z1..z3, then fused z4+epilogue
    for (int k = 1; k <= 3; k++) {
        hop2_kernel<<<gN, TB, 0, stream>>>(seg, payload, zbuf + (size_t)(k - 1) * N,
                                           dinv2, zbuf + (size_t)k * N, N);
    }
    hop2_final_kernel<<<gN, TB, 0, stream>>>(seg, payload, zbuf, x, rdinv, dinv2,
                                             W1, b1, g0, ubuf, N);

    // conv2 hops (C=16): u1..u3 (4 thr/node), then fused u4+MFMA epilogue
    for (int k = 1; k <= 3; k++) {
        hop16_kernel<<<gN4, TB, 0, stream>>>(seg, payload, ubuf + (size_t)(k - 1) * 16 * N,
                                             dinv2, ubuf + (size_t)k * 16 * N, N);
    }
    hop16_final_kernel<<<gFin, TB, 0, stream>>>(seg, payload, g0, ubuf, rdinv, dinv2,
                                                W2, b2, Wend, out, N);
}

// Round 6
// 524.923 us; speedup vs baseline: 1.1451x; 1.0269x over previous
//
#include <hip/hip_runtime.h>
#include <hip/hip_fp16.h>
#include <math.h>

// ---------------------------------------------------------------------------
// TAGConv x2 + linear + sigmoid, 500k nodes / 4M edges.
// Round 20: R19 base (539.1us) + LDS-staged coalesced-write bin_kernel.
// Theory: bin's 4M x 8B scattered writes pay write-allocate line fills
// (~8x amplification). Block already reserves contiguous per-bucket global
// ranges; staging records bucket-sorted in LDS (148KB) turns the stream-out
// into coalesced runs (~536B avg), eliminating the RMW waste.
// Conv2 gather is line-service-bound (~3.55 TB/s; R15/R16/R18 orthogonal
// nulls). Scaled-state z_k = dinv .* h_k (fp16); MFMA epilogue; single-pass
// full-bucket LDS counting-sort build (R19); paired-group gathers (R14).
// ---------------------------------------------------------------------------

#define TB 256
#define TBLD 1024
#define TBIN 1024
#define BSHIFT 11
#define BW 2048             // nodes per bucket
#define CAPB 17408          // binBuf cap (raw recs; mean 16384, ~8 sigma)
#define CAP 26624           // payload cap per bucket (8-padded; mean ~23.6k)
#define BIN_CHUNK 16384     // edges per block in bin_kernel
#define WQ 8191.0f          // 13-bit weight quantization

typedef _Float16 half8 __attribute__((ext_vector_type(8)));
typedef float floatx4 __attribute__((ext_vector_type(4)));

// Phase 1: one-pass binning. Count -> local scan -> LDS bucket-sorted stage
// -> coalesced stream-out into the block's reserved per-bucket ranges.
// rec: {src|ld<<19, w-bits}. LDS: 128KB stage + 16KB bkt + ~4KB meta.
__global__ __launch_bounds__(TBIN) void bin_kernel(
        const int* __restrict__ src, const int* __restrict__ dst,
        const float* __restrict__ w, int* __restrict__ binCount,
        uint2* __restrict__ binBuf, int E, int NB) {
    __shared__ int bcnt[256];
    __shared__ int lbase[256];
    __shared__ int grel[256];    // (global reserved start) - lbase
    __shared__ int lcur[256];
    __shared__ unsigned char bkt[BIN_CHUNK];
    __shared__ uint2 stage[BIN_CHUNK];
    for (int i = threadIdx.x; i < 256; i += TBIN) bcnt[i] = 0;
    __syncthreads();

    int base = blockIdx.x * BIN_CHUNK;
    int d[16];
#pragma unroll
    for (int j = 0; j < 16; j++) {
        int e = base + threadIdx.x + j * TBIN;
        d[j] = (e < E) ? dst[e] : -1;
        if (d[j] >= 0) atomicAdd(&bcnt[d[j] >> BSHIFT], 1);
    }
    __syncthreads();

    if (threadIdx.x == 0) {
        int run = 0;
        for (int i = 0; i < 256; i++) { lbase[i] = run; run += bcnt[i]; }
    }
    __syncthreads();
    for (int i = threadIdx.x; i < NB; i += TBIN) {
        int c = bcnt[i];
        int g = c ? atomicAdd(&binCount[i], c) : 0;
        grel[i] = g - lbase[i];
        lcur[i] = 0;
    }
    __syncthreads();

    // stage records bucket-sorted in LDS
#pragma unroll
    for (int j = 0; j < 16; j++) {
        if (d[j] >= 0) {
            int e = base + threadIdx.x + j * TBIN;
            int b = d[j] >> BSHIFT;
            int pos = lbase[b] + atomicAdd(&lcur[b], 1);
            stage[pos] = make_uint2((unsigned)src[e] | ((unsigned)(d[j] & (BW - 1)) << 19),
                                    __float_as_uint(w[e]));
            bkt[pos] = (unsigned char)b;
        }
    }
    __syncthreads();

    // coalesced stream-out (runs of ~67 recs per bucket are contiguous)
    int total = lbase[255] + bcnt[255];
    for (int i = threadIdx.x; i < total; i += TBIN) {
        int b = bkt[i];
        int rel = grel[b] + i;
        if (rel < CAPB) binBuf[(size_t)b * CAPB + rel] = stage[i];
    }
}

// Phase 2: one block per bucket. Count -> scan (8-padded) -> per-node outs ->
// SINGLE full-bucket LDS counting-sort index pass, then one coalesced payload
// stream-out (pads = 0 records). ~80KB LDS.
__global__ __launch_bounds__(TBLD) void build_kernel(
        const int* __restrict__ binCount, const uint2* __restrict__ binBuf,
        unsigned* __restrict__ payload, int* __restrict__ seg,
        float* __restrict__ dinv2, float* __restrict__ rdinv,
        const float* __restrict__ x, __half2* __restrict__ z0,
        int N, int NB) {
    __shared__ int   cnt[BW];
    __shared__ float wsum[BW];
    __shared__ int   start[BW];
    __shared__ unsigned short ord[CAP];
    __shared__ int   tmp[TBLD];
    __shared__ int   stot;
    int b = blockIdx.x;
    int nBase = b << BSHIFT;
    int nCount = min(BW, N - nBase);
    int m = min(binCount[b], CAPB);

    for (int i = threadIdx.x; i < BW; i += TBLD) { cnt[i] = 0; wsum[i] = 0.0f; }
    __syncthreads();

    const uint2* recs = binBuf + (size_t)b * CAPB;
    for (int i = threadIdx.x; i < m; i += TBLD) {
        uint2 r = recs[i];
        int ld = r.x >> 19;
        atomicAdd(&cnt[ld], 1);
        atomicAdd(&wsum[ld], __uint_as_float(r.y));
    }
    __syncthreads();

    // exclusive scan of 8-padded counts, 2 elems/thread
    int b2i = threadIdx.x * 2;
    int c0 = (cnt[b2i] + 7) & ~7;
    int c1 = (cnt[b2i + 1] + 7) & ~7;
    int s = c0 + c1;
    tmp[threadIdx.x] = s;
    __syncthreads();
    for (int off = 1; off < TBLD; off <<= 1) {
        int t = (threadIdx.x >= off) ? tmp[threadIdx.x - off] : 0;
        __syncthreads();
        tmp[threadIdx.x] += t;
        __syncthreads();
    }
    int run = tmp[threadIdx.x] - s;
    start[b2i] = run;
    start[b2i + 1] = run + c0;
    if (threadIdx.x == TBLD - 1) stot = run + s;   // total padded size
    __syncthreads();

    int tot = min(stot, CAP);

    // per-node outputs
    for (int i = threadIdx.x; i < nCount; i += TBLD) {
        int n = nBase + i;
        int cc = cnt[i];
        int st = start[i];
        int ng = (cc + 7) >> 3;
        if (st >= CAP) { ng = 0; }
        else if (st + 8 * ng > CAP) { ng = (CAP - st) >> 3; }
        seg[n] = (st >> 3) | (ng << 16);
        float dsum = wsum[i];
        float di = (dsum > 0.0f) ? rsqrtf(dsum) : 0.0f;
        dinv2[n] = di * di;
        rdinv[n] = dsum * di;            // sqrt(deg), 0 if deg==0
        float2 xv = reinterpret_cast<const float2*>(x)[n];
        z0[n] = __float22half2_rn(make_float2(di * xv.x, di * xv.y));
    }
    __syncthreads();

    // cursors (reuse cnt) + ord init over the full bucket
    for (int i = threadIdx.x; i < nCount; i += TBLD) cnt[i] = start[i];
    for (int j = threadIdx.x; j < tot; j += TBLD) ord[j] = 0xFFFF;
    __syncthreads();

    // single counting-sort index pass
    for (int i = threadIdx.x; i < m; i += TBLD) {
        uint2 r = recs[i];
        int ld = r.x >> 19;
        int pos = atomicAdd(&cnt[ld], 1);
        if ((unsigned)pos < (unsigned)tot) ord[pos] = (unsigned short)i;
    }
    __syncthreads();

    // coalesced stream-out (random reads hit L2-resident recs)
    size_t pbase = (size_t)b * CAP;
    for (int j = threadIdx.x; j < tot; j += TBLD) {
        unsigned short oi = ord[j];
        unsigned word = 0;
        if (oi != 0xFFFF) {
            uint2 r = recs[oi];
            unsigned q = (unsigned)__float2int_rn(__uint_as_float(r.y) * WQ);
            word = (r.x & 0x7FFFFu) | (q << 19);
        }
        payload[pbase + j] = word;
    }
}

// ---- gather helpers: full groups of 8, paired-group MLP, no masks ---------

// C=2
__device__ __forceinline__ void gacc2m(const unsigned* __restrict__ payload,
                                       const __half2* __restrict__ zin,
                                       int beg, int ng, float& ax, float& ay) {
    int g = 0;
    for (; g + 2 <= ng; g += 2, beg += 16) {
        uint4 r0 = *reinterpret_cast<const uint4*>(payload + beg);
        uint4 r1 = *reinterpret_cast<const uint4*>(payload + beg + 4);
        uint4 r2 = *reinterpret_cast<const uint4*>(payload + beg + 8);
        uint4 r3 = *reinterpret_cast<const uint4*>(payload + beg + 12);
        unsigned r[16] = {r0.x, r0.y, r0.z, r0.w, r1.x, r1.y, r1.z, r1.w,
                          r2.x, r2.y, r2.z, r2.w, r3.x, r3.y, r3.z, r3.w};
        __half2 v[16];
#pragma unroll
        for (int j = 0; j < 16; j++) v[j] = zin[r[j] & 0x7FFFFu];
#pragma unroll
        for (int j = 0; j < 16; j++) {
            float wv = (float)(r[j] >> 19) * (1.0f / WQ);
            float2 f = __half22float2(v[j]);
            ax += wv * f.x;
            ay += wv * f.y;
        }
    }
    if (g < ng) {
        uint4 r0 = *reinterpret_cast<const uint4*>(payload + beg);
        uint4 r1 = *reinterpret_cast<const uint4*>(payload + beg + 4);
        unsigned r[8] = {r0.x, r0.y, r0.z, r0.w, r1.x, r1.y, r1.z, r1.w};
        __half2 v[8];
#pragma unroll
        for (int j = 0; j < 8; j++) v[j] = zin[r[j] & 0x7FFFFu];
#pragma unroll
        for (int j = 0; j < 8; j++) {
            float wv = (float)(r[j] >> 19) * (1.0f / WQ);
            float2 f = __half22float2(v[j]);
            ax += wv * f.x;
            ay += wv * f.y;
        }
    }
}

// C=4 (quarter-row); ubase = uin + 4*quarter.
__device__ __forceinline__ void gacc4(const unsigned* __restrict__ payload,
                                      const __half* __restrict__ ubase,
                                      int beg, int ng, float* __restrict__ h) {
    int g = 0;
    for (; g + 2 <= ng; g += 2, beg += 16) {
        uint4 r0 = *reinterpret_cast<const uint4*>(payload + beg);
        uint4 r1 = *reinterpret_cast<const uint4*>(payload + beg + 4);
        uint4 r2 = *reinterpret_cast<const uint4*>(payload + beg + 8);
        uint4 r3 = *reinterpret_cast<const uint4*>(payload + beg + 12);
        unsigned r[16] = {r0.x, r0.y, r0.z, r0.w, r1.x, r1.y, r1.z, r1.w,
                          r2.x, r2.y, r2.z, r2.w, r3.x, r3.y, r3.z, r3.w};
        float2 a[16];
#pragma unroll
        for (int j = 0; j < 16; j++)
            a[j] = *reinterpret_cast<const float2*>(ubase + 16LL * (int)(r[j] & 0x7FFFFu));
#pragma unroll
        for (int j = 0; j < 16; j++) {
            float wv = (float)(r[j] >> 19) * (1.0f / WQ);
            const __half2* hp = reinterpret_cast<const __half2*>(&a[j]);
            float2 v0 = __half22float2(hp[0]);
            float2 v1 = __half22float2(hp[1]);
            h[0] += wv * v0.x;
            h[1] += wv * v0.y;
            h[2] += wv * v1.x;
            h[3] += wv * v1.y;
        }
    }
    if (g < ng) {
        uint4 r0 = *reinterpret_cast<const uint4*>(payload + beg);
        uint4 r1 = *reinterpret_cast<const uint4*>(payload + beg + 4);
        unsigned r[8] = {r0.x, r0.y, r0.z, r0.w, r1.x, r1.y, r1.z, r1.w};
        float2 a[8];
#pragma unroll
        for (int j = 0; j < 8; j++)
            a[j] = *reinterpret_cast<const float2*>(ubase + 16LL * (int)(r[j] & 0x7FFFFu));
#pragma unroll
        for (int j = 0; j < 8; j++) {
            float wv = (float)(r[j] >> 19) * (1.0f / WQ);
            const __half2* hp = reinterpret_cast<const __half2*>(&a[j]);
            float2 v0 = __half22float2(hp[0]);
            float2 v1 = __half22float2(hp[1]);
            h[0] += wv * v0.x;
            h[1] += wv * v0.y;
            h[2] += wv * v1.x;
            h[3] += wv * v1.y;
        }
    }
}

// ----------------------------------------------------------------------------

// z_k[n] = dinv2[n] * sum w * z_{k-1}[src]   (C=2, fp16 state), k=1..3
__global__ void hop2_kernel(const int* __restrict__ seg, const unsigned* __restrict__ payload,
                            const __half2* __restrict__ zin, const float* __restrict__ dinv2,
                            __half2* __restrict__ zout, int N) {
    int n = blockIdx.x * TB + threadIdx.x;
    if (n >= N) return;
    int sp = seg[n];
    int beg = (n >> BSHIFT) * CAP + ((sp & 0xFFFF) << 3);
    int ng = sp >> 16;
    float ax = 0.0f, ay = 0.0f;
    gacc2m(payload, zin, beg, ng, ax, ay);
    float sc = dinv2[n];
    zout[n] = __float22half2_rn(make_float2(ax * sc, ay * sc));
}

// Fused hop2 k=4 + conv1 epilogue
__global__ void hop2_final_kernel(const int* __restrict__ seg, const unsigned* __restrict__ payload,
                                  const __half2* __restrict__ zbuf,   // z0..z3
                                  const float* __restrict__ x,
                                  const float* __restrict__ rdinv, const float* __restrict__ dinv2,
                                  const float* __restrict__ W1, const float* __restrict__ b1,
                                  __half* __restrict__ g0, __half* __restrict__ u0, int N) {
    __shared__ float Ws[160];
    __shared__ float bs[16];
    for (int i = threadIdx.x; i < 160; i += blockDim.x) Ws[i] = W1[i];
    if (threadIdx.x < 16) bs[threadIdx.x] = b1[threadIdx.x];
    __syncthreads();

    int n = blockIdx.x * TB + threadIdx.x;
    if (n >= N) return;

    int sp = seg[n];
    int beg = (n >> BSHIFT) * CAP + ((sp & 0xFFFF) << 3);
    int ng = sp >> 16;
    const __half2* z3 = zbuf + (size_t)3 * N;
    float ax = 0.0f, ay = 0.0f;
    gacc2m(payload, z3, beg, ng, ax, ay);
    float sc = dinv2[n];
    float rd = rdinv[n];

    float coeff[10];
    {
        float2 v = reinterpret_cast<const float2*>(x)[n];
        coeff[0] = v.x; coeff[1] = v.y;
    }
#pragma unroll
    for (int k = 1; k <= 3; k++) {
        float2 v = __half22float2(zbuf[(size_t)k * N + n]);
        coeff[2 * k + 0] = rd * v.x;
        coeff[2 * k + 1] = rd * v.y;
    }
    coeff[8] = rd * sc * ax;
    coeff[9] = rd * sc * ay;

    float o[16];
#pragma unroll
    for (int c = 0; c < 16; c++) o[c] = bs[c];
#pragma unroll
    for (int j = 0; j < 10; j++) {
        float cf = coeff[j];
#pragma unroll
        for (int c = 0; c < 16; c++) o[c] += cf * Ws[j * 16 + c];
    }
#pragma unroll
    for (int c = 0; c < 16; c++) o[c] = fmaxf(o[c], 0.0f);

    float di = sc * rd;   // = dinv (0 for deg-0 nodes)

    __half2 gp[8], up[8];
#pragma unroll
    for (int q = 0; q < 8; q++) {
        gp[q] = __float22half2_rn(make_float2(o[2 * q], o[2 * q + 1]));
        up[q] = __float22half2_rn(make_float2(di * o[2 * q], di * o[2 * q + 1]));
    }
    float4* gw = reinterpret_cast<float4*>(g0 + 16LL * n);
    gw[0] = *reinterpret_cast<float4*>(&gp[0]);
    gw[1] = *reinterpret_cast<float4*>(&gp[4]);
    float4* uw = reinterpret_cast<float4*>(u0 + 16LL * n);
    uw[0] = *reinterpret_cast<float4*>(&up[0]);
    uw[1] = *reinterpret_cast<float4*>(&up[4]);
}

// u_k = dinv2 * sum w * u_{k-1}[src]; 4 threads per node (4 channels each)
__global__ void hop16_kernel(const int* __restrict__ seg, const unsigned* __restrict__ payload,
                             const __half* __restrict__ uin, const float* __restrict__ dinv2,
                             __half* __restrict__ uout, int N) {
    int gid = blockIdx.x * TB + threadIdx.x;
    int n = gid >> 2, quarter = gid & 3;
    if (n >= N) return;
    int sp = seg[n];
    int beg = (n >> BSHIFT) * CAP + ((sp & 0xFFFF) << 3);
    int ng = sp >> 16;

    float h[4] = {0.0f, 0.0f, 0.0f, 0.0f};
    gacc4(payload, uin + 4 * quarter, beg, ng, h);

    float sc = dinv2[n];
    __half2 p[2];
    p[0] = __float22half2_rn(make_float2(h[0] * sc, h[1] * sc));
    p[1] = __float22half2_rn(make_float2(h[2] * sc, h[3] * sc));
    *reinterpret_cast<float2*>(uout + 16LL * n + 4 * quarter) = *reinterpret_cast<float2*>(&p[0]);
}

// Fused hop16 k=4 + conv2 epilogue via MFMA + endLinear + sigmoid.
// Wave = 16 nodes x 4 quads; node=lane&15, quarter=lane>>4.
__global__ void hop16_final_kernel(const int* __restrict__ seg, const unsigned* __restrict__ payload,
                                   const __half* __restrict__ g0, const __half* __restrict__ ubuf,
                                   const float* __restrict__ rdinv, const float* __restrict__ dinv2,
                                   const float* __restrict__ W2, const float* __restrict__ b2,
                                   const float* __restrict__ Wend, float* __restrict__ out, int N) {
    int lane = threadIdx.x & 63;
    int wave = threadIdx.x >> 6;
    int q = lane >> 4;           // quad -> K-chunk
    int nn = lane & 15;          // node row m / output column n
    int node_base = (blockIdx.x * 4 + wave) * 16;
    int node = node_base + nn;
    int nodec = min(node, N - 1);

    // B fragments: lane supplies B[K=32t+8q+i][n=nn] from W2 (fp32->fp16)
    half8 bf[3];
#pragma unroll
    for (int t = 0; t < 3; t++) {
        half8 bv;
#pragma unroll
        for (int i = 0; i < 8; i++) {
            int K = 32 * t + 8 * q + i;
            K = (K < 80) ? K : 79;          // pad rows never used (A=0 there)
            bv[i] = (_Float16)W2[K * 16 + nn];
        }
        bf[t] = bv;
    }
    float bsv = b2[nn];
    float wev = Wend[nn];

    // gather k=4 term: h = quarter q (channels 4q..4q+3) of node's u4 row
    int sp = seg[nodec];
    int beg = (nodec >> BSHIFT) * CAP + ((sp & 0xFFFF) << 3);
    int ng = sp >> 16;
    const __half* u3 = ubuf + (size_t)3 * 16 * N;
    float h[4] = {0.0f, 0.0f, 0.0f, 0.0f};
    gacc4(payload, u3 + 4 * q, beg, ng, h);

    float rd = rdinv[nodec];
    float sc = dinv2[nodec];

    // A fragment t=0: q0,q1 -> g0 (raw); q2,q3 -> u1 (x rd)
    const __half* a0p = ((q < 2) ? g0 : (ubuf + (size_t)16 * N)) + 16LL * nodec + 8 * (q & 1);
    half8 a0 = *reinterpret_cast<const half8*>(a0p);
    a0 = a0 * ((q >= 2) ? (_Float16)rd : (_Float16)1.0f);

    // A fragment t=1: q0,q1 -> u2; q2,q3 -> u3 (all x rd)
    const __half* a1p = ((q < 2) ? (ubuf + (size_t)2 * 16 * N) : (ubuf + (size_t)3 * 16 * N))
                        + 16LL * nodec + 8 * (q & 1);
    half8 a1 = *reinterpret_cast<const half8*>(a1p);
    a1 = a1 * (_Float16)rd;

    // A fragment t=2: q0,q1 -> h (x rd*sc) via shfl repack; q2,q3 -> zero pad
    float s4 = rd * sc;
    __half2 hh0 = __floats2half2_rn(h[0] * s4, h[1] * s4);
    __half2 hh1 = __floats2half2_rn(h[2] * s4, h[3] * s4);
    int p0, p1;
    p0 = *reinterpret_cast<int*>(&hh0);
    p1 = *reinterpret_cast<int*>(&hh1);
    int srcA = (nn + (q << 5)) & 63;   // q0: quarters 0,1 ; q1: quarters 2,3
    int srcB = (srcA + 16) & 63;
    int lo0 = __shfl(p0, srcA, 64);
    int lo1 = __shfl(p1, srcA, 64);
    int hi0 = __shfl(p0, srcB, 64);
    int hi1 = __shfl(p1, srcB, 64);
    if (q >= 2) { lo0 = 0; lo1 = 0; hi0 = 0; hi1 = 0; }
    union { half8 v; int u[4]; } a2;
    a2.u[0] = lo0; a2.u[1] = lo1; a2.u[2] = hi0; a2.u[3] = hi1;

    floatx4 acc = {bsv, bsv, bsv, bsv};
    acc = __builtin_amdgcn_mfma_f32_16x16x32_f16(a0, bf[0], acc, 0, 0, 0);
    acc = __builtin_amdgcn_mfma_f32_16x16x32_f16(a1, bf[1], acc, 0, 0, 0);
    acc = __builtin_amdgcn_mfma_f32_16x16x32_f16(a2.v, bf[2], acc, 0, 0, 0);

    // D[m = q*4+reg][n = nn]: relu, dot with Wend over n, sigmoid, store
    float svals[4];
#pragma unroll
    for (int r = 0; r < 4; r++) {
        float o = fmaxf(acc[r], 0.0f) * wev;
        o += __shfl_xor(o, 1, 64);
        o += __shfl_xor(o, 2, 64);
        o += __shfl_xor(o, 4, 64);
        o += __shfl_xor(o, 8, 64);
        svals[r] = o;
    }
    if (nn == 0) {
#pragma unroll
        for (int r = 0; r < 4; r++) {
            int on = node_base + q * 4 + r;
            if (on < N) out[on] = 1.0f / (1.0f + __expf(-svals[r]));
        }
    }
}

extern "C" void kernel_launch(void* const* d_in, const int* in_sizes, int n_in,
                              void* d_out, int out_size, void* d_ws, size_t ws_size,
                              hipStream_t stream) {
    const float* x    = (const float*)d_in[0];
    const int*   ei   = (const int*)d_in[1];
    const float* w    = (const float*)d_in[2];
    const float* W1   = (const float*)d_in[3];
    const float* b1   = (const float*)d_in[4];
    const float* W2   = (const float*)d_in[5];
    const float* b2   = (const float*)d_in[6];
    const float* Wend = (const float*)d_in[7];
    float* out = (float*)d_out;

    const int N = in_sizes[0] / 2;   // 500000
    const int E = in_sizes[2];       // 4000000
    const int NB = (N + BW - 1) / BW;  // 245

    const int* src = ei;
    const int* dst = ei + E;

    // workspace layout: binCount 4KB | payload 26.1MB | seg 2MB | dinv2 2MB |
    // rdinv 2MB | zbuf 8MB (z0..z3) | g0 16MB | ubuf 64MB (u0..u3);
    // binBuf (34.1MB) aliased over u1..u3 (48MB; dead after build)
    int*      binCount = (int*)d_ws;
    unsigned* payload  = (unsigned*)(binCount + 1024);
    int*      seg      = (int*)(payload + (size_t)NB * CAP);
    float*    dinv2    = (float*)(seg + N);
    float*    rdinv    = dinv2 + N;
    __half2*  zbuf     = (__half2*)(rdinv + N);
    __half*   g0       = (__half*)(zbuf + (size_t)4 * N);
    __half*   ubuf     = g0 + (size_t)16 * N;
    uint2*    binBuf   = (uint2*)(ubuf + (size_t)16 * N);   // over u1..u3

    const int gE_bin = (E + BIN_CHUNK - 1) / BIN_CHUNK;   // 245
    const int gN   = (N + TB - 1) / TB;                   // 1954
    const int gN4  = (4 * N + TB - 1) / TB;               // 7813
    const int gFin = (N + 63) / 64;                       // 7813 (64 nodes/block)

    hipMemsetAsync(binCount, 0, 1024 * sizeof(int), stream);

    // CSR build
    bin_kernel<<<gE_bin, TBIN, 0, stream>>>(src, dst, w, binCount, binBuf, E, NB);
    build_kernel<<<NB, TBLD, 0, stream>>>(binCount, binBuf, payload, seg, dinv2, rdinv, x, zbuf, N, NB);

    // conv1 hops (C=2): z1..z3, then fused z4+epilogue
    for (int k = 1; k <= 3; k++) {
        hop2_kernel<<<gN, TB, 0, stream>>>(seg, payload, zbuf + (size_t)(k - 1) * N,
                                           dinv2, zbuf + (size_t)k * N, N);
    }
    hop2_final_kernel<<<gN, TB, 0, stream>>>(seg, payload, zbuf, x, rdinv, dinv2,
                                             W1, b1, g0, ubuf, N);

    // conv2 hops (C=16): u1..u3 (4 thr/node), then fused u4+MFMA epilogue
    for (int k = 1; k <= 3; k++) {
        hop16_kernel<<<gN4, TB, 0, stream>>>(seg, payload, ubuf + (size_t)(k - 1) * 16 * N,
                                             dinv2, ubuf + (size_t)k * 16 * N, N);
    }
    hop16_final_kernel<<<gFin, TB, 0, stream>>>(seg, payload, g0, ubuf, rdinv, dinv2,
                                                W2, b2, Wend, out, N);
}